// Round 5
// baseline (1179.429 us; speedup 1.0000x reference)
//
#include <hip/hip_runtime.h>

namespace {

typedef __attribute__((ext_vector_type(8))) short short8;
typedef __attribute__((ext_vector_type(4))) float f32x4;

constexpr int kNP = 50000, kNT = 200000, kNA = 20000;
constexpr int kEPT = 1000000, kETP = 1000000, kEAT = 400000, kETA = 400000;
constexpr int DIN = 128, DH = 256, DO = 128;

__device__ __forceinline__ float bf2f(short u) {
  union { unsigned int i; float f; } c;
  c.i = ((unsigned int)(unsigned short)u) << 16;
  return c.f;
}
__device__ __forceinline__ short f2bf(float f) {
  union { float f; unsigned int i; } c;
  c.f = f;
  unsigned int r = c.i + 0x7fffu + ((c.i >> 16) & 1u);  // RNE
  return (short)(r >> 16);
}

// ---------------- converts ----------------

template <bool ADD>
__global__ __launch_bounds__(256) void cvt_bf16(const float* __restrict__ a,
                                                const float* __restrict__ b,
                                                short* __restrict__ o, int n8) {
  int g = blockIdx.x * 256 + threadIdx.x;
  if (g >= n8) return;
  const float4* a4 = reinterpret_cast<const float4*>(a);
  float4 x0 = a4[2 * g], x1 = a4[2 * g + 1];
  if constexpr (ADD) {
    const float4* b4 = reinterpret_cast<const float4*>(b);
    float4 y0 = b4[2 * g], y1 = b4[2 * g + 1];
    x0.x += y0.x; x0.y += y0.y; x0.z += y0.z; x0.w += y0.w;
    x1.x += y1.x; x1.y += y1.y; x1.z += y1.z; x1.w += y1.w;
  }
  short8 w;
  w[0] = f2bf(x0.x); w[1] = f2bf(x0.y); w[2] = f2bf(x0.z); w[3] = f2bf(x0.w);
  w[4] = f2bf(x1.x); w[5] = f2bf(x1.y); w[6] = f2bf(x1.z); w[7] = f2bf(x1.w);
  reinterpret_cast<short8*>(o)[g] = w;
}

// ---------------- weight prep (bf16, native [out][in] layout) ----------------

__global__ __launch_bounds__(256) void scale4_bf16(const float* __restrict__ in,
                                                   short* __restrict__ out,
                                                   int per, float s0, float s1,
                                                   float s2, float s3) {
  int g = blockIdx.x * 256 + threadIdx.x;
  if (g >= 4 * per) return;
  int e = g / per;
  float s = (e == 0) ? s0 : (e == 1) ? s1 : (e == 2) ? s2 : s3;
  out[g] = f2bf(in[g] * s);
}

__global__ __launch_bounds__(256) void wsum2_bf16(const float* __restrict__ in1,
                                                  const float* __restrict__ in2,
                                                  short* __restrict__ out, int n,
                                                  float sa, float sb) {
  int g = blockIdx.x * 256 + threadIdx.x;
  if (g < n) out[g] = f2bf(sa * in1[g] + sb * in2[g]);
}

// Wc[0] (track):    Wres[1] + 0.5*(W2r[0]+W2r[2])
// Wc[1] (playlist): Wres[0] + W2r[1]
// Wc[2] (artist):   Wres[2] + W2r[3];  bc likewise from bres/b2 (fp32).
__global__ __launch_bounds__(256) void prep_wc(const float* __restrict__ Wres,
                                               const float* __restrict__ W2r,
                                               const float* __restrict__ bres,
                                               const float* __restrict__ b2,
                                               short* __restrict__ Wc,
                                               float* __restrict__ bc) {
  int gid = blockIdx.x * 256 + threadIdx.x;
  const int per = DO * DH;
  if (gid < 3 * per) {
    int b = gid / per;
    int idx = gid - b * per;
    int resIdx = (b == 0) ? 1 : (b == 1) ? 0 : 2;
    float v = Wres[(size_t)resIdx * per + idx];
    if (b == 0)
      v += 0.5f * (W2r[(size_t)0 * per + idx] + W2r[(size_t)2 * per + idx]);
    else if (b == 1)
      v += W2r[(size_t)1 * per + idx];
    else
      v += W2r[(size_t)3 * per + idx];
    Wc[gid] = f2bf(v);
  }
  if (gid < 3 * DO) {
    int b = gid / DO;
    int o = gid - b * DO;
    int resIdx = (b == 0) ? 1 : (b == 1) ? 0 : 2;
    float v = bres[resIdx * DO + o];
    if (b == 0)
      v += 0.5f * (b2[0 * DO + o] + b2[2 * DO + o]);
    else if (b == 1)
      v += b2[1 * DO + o];
    else
      v += b2[3 * DO + o];
    bc[gid] = v;
  }
}

__global__ __launch_bounds__(256) void prep_b1ct(const float* __restrict__ b1,
                                                 float* __restrict__ o) {
  int g = blockIdx.x * 256 + threadIdx.x;
  if (g < DH) o[g] = 0.5f * (b1[g] + b1[2 * DH + g]);
}

// ---------------- CSR build ----------------

__global__ __launch_bounds__(256) void hist_kernel(const int* __restrict__ dst,
                                                   int E, int* __restrict__ cnt) {
  int g = blockIdx.x * 256 + threadIdx.x;
  if (g < E) atomicAdd(&cnt[dst[g]], 1);
}

__global__ __launch_bounds__(256) void scan1(const int* __restrict__ cnt,
                                             int* __restrict__ part, int N) {
  __shared__ int s[256];
  int g = blockIdx.x * 256 + threadIdx.x;
  int t = threadIdx.x;
  s[t] = (g < N) ? cnt[g] : 0;
  __syncthreads();
  for (int o = 128; o > 0; o >>= 1) {
    if (t < o) s[t] += s[t + o];
    __syncthreads();
  }
  if (t == 0) part[blockIdx.x] = s[0];
}

__global__ __launch_bounds__(1024) void scan2(int* __restrict__ part, int nb) {
  __shared__ int s[1024];
  int t = threadIdx.x;
  int v = (t < nb) ? part[t] : 0;
  s[t] = v;
  __syncthreads();
  for (int o = 1; o < 1024; o <<= 1) {
    int x = (t >= o) ? s[t - o] : 0;
    __syncthreads();
    s[t] += x;
    __syncthreads();
  }
  if (t < nb) part[t] = s[t] - v;  // exclusive
}

__global__ __launch_bounds__(256) void scan3(const int* __restrict__ cnt,
                                             const int* __restrict__ part,
                                             int* __restrict__ rp,
                                             int* __restrict__ cursor, int N,
                                             int E) {
  __shared__ int s[256];
  int g = blockIdx.x * 256 + threadIdx.x;
  int t = threadIdx.x;
  int v = (g < N) ? cnt[g] : 0;
  s[t] = v;
  __syncthreads();
  for (int o = 1; o < 256; o <<= 1) {
    int x = (t >= o) ? s[t - o] : 0;
    __syncthreads();
    s[t] += x;
    __syncthreads();
  }
  if (g < N) {
    int excl = s[t] - v + part[blockIdx.x];
    rp[g] = excl;
    cursor[g] = excl;
    if (g == N - 1) rp[N] = E;
  }
}

__global__ __launch_bounds__(256) void fill_csr(const int* __restrict__ src,
                                                const int* __restrict__ dst,
                                                int E, int* __restrict__ cursor,
                                                int* __restrict__ col) {
  int g = blockIdx.x * 256 + threadIdx.x;
  if (g < E) {
    int p = atomicAdd(&cursor[dst[g]], 1);
    col[p] = src[g];
  }
}

// ---------------- gathers (bf16 in, fp32 accumulate, bf16 out) ----------------

template <int D8>
__global__ __launch_bounds__(256) void gather_b(const short* __restrict__ X,
                                                const int* __restrict__ rp,
                                                const int* __restrict__ col,
                                                short* __restrict__ out, int N) {
  constexpr int NG = 256 / D8;
  int g = blockIdx.x * NG + (int)threadIdx.x / D8;
  int c = (int)threadIdx.x % D8;
  if (g >= N) return;
  int s = rp[g], e = rp[g + 1];
  float acc[8] = {0.f, 0.f, 0.f, 0.f, 0.f, 0.f, 0.f, 0.f};
  const short8* Xv = reinterpret_cast<const short8*>(X);
  for (int j = s; j < e; ++j) {
    short8 v = Xv[(size_t)col[j] * D8 + c];
#pragma unroll
    for (int i = 0; i < 8; ++i) acc[i] += bf2f(v[i]);
  }
  float inv = 1.0f / fmaxf((float)(e - s), 1.0f);
  short8 w;
#pragma unroll
  for (int i = 0; i < 8; ++i) w[i] = f2bf(acc[i] * inv);
  reinterpret_cast<short8*>(out)[(size_t)g * D8 + c] = w;
}

// out[g] = bf16( mean1(X1 over csr1) + mean2(X2 over csr2) )
template <int D8>
__global__ __launch_bounds__(256) void gather2_b(
    const short* __restrict__ X1, const int* __restrict__ rp1,
    const int* __restrict__ col1, const short* __restrict__ X2,
    const int* __restrict__ rp2, const int* __restrict__ col2,
    short* __restrict__ out, int N) {
  constexpr int NG = 256 / D8;
  int g = blockIdx.x * NG + (int)threadIdx.x / D8;
  int c = (int)threadIdx.x % D8;
  if (g >= N) return;
  float tot[8] = {0.f, 0.f, 0.f, 0.f, 0.f, 0.f, 0.f, 0.f};
  {
    int s = rp1[g], e = rp1[g + 1];
    float a[8] = {0.f, 0.f, 0.f, 0.f, 0.f, 0.f, 0.f, 0.f};
    const short8* Xv = reinterpret_cast<const short8*>(X1);
    for (int j = s; j < e; ++j) {
      short8 v = Xv[(size_t)col1[j] * D8 + c];
#pragma unroll
      for (int i = 0; i < 8; ++i) a[i] += bf2f(v[i]);
    }
    float inv = 1.0f / fmaxf((float)(e - s), 1.0f);
#pragma unroll
    for (int i = 0; i < 8; ++i) tot[i] += a[i] * inv;
  }
  {
    int s = rp2[g], e = rp2[g + 1];
    float a[8] = {0.f, 0.f, 0.f, 0.f, 0.f, 0.f, 0.f, 0.f};
    const short8* Xv = reinterpret_cast<const short8*>(X2);
    for (int j = s; j < e; ++j) {
      short8 v = Xv[(size_t)col2[j] * D8 + c];
#pragma unroll
      for (int i = 0; i < 8; ++i) a[i] += bf2f(v[i]);
    }
    float inv = 1.0f / fmaxf((float)(e - s), 1.0f);
#pragma unroll
    for (int i = 0; i < 8; ++i) tot[i] += a[i] * inv;
  }
  short8 w;
#pragma unroll
  for (int i = 0; i < 8; ++i) w[i] = f2bf(tot[i]);
  reinterpret_cast<short8*>(out)[(size_t)g * D8 + c] = w;
}

// ---------------- MFMA GEMM v2 (B-in-registers, A LDS-swizzled) ----------------
// C[n][o] = relu?( sum_a A_a[n][:] . B_a[o][:] + bias[o] + bf2f(add0[n][o]) )
// A_a: [N][K] bf16 row-major; B_a: [DOUT][K] bf16 row-major.
template <int K, int DOUT, int NA, bool BF16OUT, bool BIAS, bool RELU,
          bool HASADD>
__global__ __launch_bounds__(256) void mfma_gemm(
    const short* __restrict__ A0, const short* __restrict__ A1,
    const short* __restrict__ A2, const short* __restrict__ B0,
    const short* __restrict__ B1, const short* __restrict__ B2,
    const float* __restrict__ bias, const short* __restrict__ add0,
    float* __restrict__ Cf, short* __restrict__ Cb, int N) {
  constexpr int WC = DOUT / 64;  // col-waves (4 for 256, 2 for 128)
  constexpr int WR = 4 / WC;     // row-panels (1 or 2)
  constexpr int ROWS = WR * 64;
  constexpr int KC = 128;        // K-chunk staged in LDS

  __shared__ short As[ROWS * KC];  // swizzled: idx ^= (row&7)<<3

  const int tid = threadIdx.x;
  const int lane = tid & 63;
  const int w = tid >> 6;
  const int wr = w / WC;
  const int wc = w % WC;
  const int lr = lane & 15;
  const int ls = lane >> 4;
  const int n0 = blockIdx.x * ROWS;

  const short* Ap[3] = {A0, A1, A2};
  const short* Bp[3] = {B0, B1, B2};

  f32x4 acc[4][4] = {};  // [tm][tn]

  bool first = true;
#pragma unroll
  for (int a = 0; a < NA; ++a) {
#pragma unroll
    for (int kc0 = 0; kc0 < K; kc0 += KC) {
      if (!first) __syncthreads();
      first = false;
      // stage A rows [n0, n0+ROWS) x k [kc0, kc0+KC) -> swizzled LDS
#pragma unroll
      for (int i = 0; i < ROWS / 16; ++i) {
        int idx = i * 256 + tid;
        int row = idx >> 4;
        int c8 = idx & 15;
        short8 v = {0, 0, 0, 0, 0, 0, 0, 0};
        int n = n0 + row;
        if (n < N)
          v = *reinterpret_cast<const short8*>(Ap[a] + (size_t)n * K + kc0 +
                                               c8 * 8);
        *reinterpret_cast<short8*>(
            &As[(row * KC + c8 * 8) ^ ((row & 7) << 3)]) = v;
      }
      __syncthreads();
#pragma unroll
      for (int kh = 0; kh < 2; ++kh) {
        short8 bfr[2][4];
#pragma unroll
        for (int kq = 0; kq < 2; ++kq)
#pragma unroll
          for (int tn = 0; tn < 4; ++tn)
            bfr[kq][tn] = *reinterpret_cast<const short8*>(
                Bp[a] + (size_t)(wc * 64 + tn * 16 + lr) * K + kc0 +
                (kh * 2 + kq) * 32 + ls * 8);
#pragma unroll
        for (int kq = 0; kq < 2; ++kq) {
          int kk = kh * 2 + kq;
#pragma unroll
          for (int tm = 0; tm < 4; ++tm) {
            int row = wr * 64 + tm * 16 + lr;
            short8 af = *reinterpret_cast<const short8*>(
                &As[(row * KC + kk * 32 + ls * 8) ^ ((row & 7) << 3)]);
#pragma unroll
            for (int tn = 0; tn < 4; ++tn)
              acc[tm][tn] = __builtin_amdgcn_mfma_f32_16x16x32_bf16(
                  af, bfr[kq][tn], acc[tm][tn], 0, 0, 0);
          }
        }
      }
    }
  }

  // epilogue: row = n0 + wr*64 + tm*16 + ls*4 + r, col = wc*64 + tn*16 + lr
#pragma unroll
  for (int tm = 0; tm < 4; ++tm) {
#pragma unroll
    for (int tn = 0; tn < 4; ++tn) {
      int colg = wc * 64 + tn * 16 + lr;
      float bv = 0.f;
      if constexpr (BIAS) bv = bias[colg];
#pragma unroll
      for (int r = 0; r < 4; ++r) {
        int n = n0 + wr * 64 + tm * 16 + ls * 4 + r;
        if (n < N) {
          float v = acc[tm][tn][r] + bv;
          if constexpr (HASADD) v += bf2f(add0[(size_t)n * DOUT + colg]);
          if constexpr (RELU) v = fmaxf(v, 0.f);
          if constexpr (BF16OUT)
            Cb[(size_t)n * DOUT + colg] = f2bf(v);
          else
            Cf[(size_t)n * DOUT + colg] = v;
        }
      }
    }
  }
}

inline int cdiv(int a, int b) { return (a + b - 1) / b; }

}  // namespace

extern "C" void kernel_launch(void* const* d_in, const int* in_sizes, int n_in,
                              void* d_out, int out_size, void* d_ws,
                              size_t ws_size, hipStream_t stream) {
  const float* x_p   = (const float*)d_in[0];
  const float* x_t   = (const float*)d_in[1];
  const float* x_a   = (const float*)d_in[2];
  const float* emb_p = (const float*)d_in[3];
  const float* emb_a = (const float*)d_in[4];
  const float* W1l   = (const float*)d_in[5];
  const float* b1    = (const float*)d_in[6];
  const float* W1r   = (const float*)d_in[7];
  const float* W2l   = (const float*)d_in[8];
  const float* b2    = (const float*)d_in[9];
  const float* W2r   = (const float*)d_in[10];
  const float* Wres  = (const float*)d_in[11];
  const float* bres  = (const float*)d_in[12];
  const int* e_pt = (const int*)d_in[13];
  const int* e_tp = (const int*)d_in[14];
  const int* e_at = (const int*)d_in[15];
  const int* e_ta = (const int*)d_in[16];
  (void)in_sizes; (void)n_in; (void)out_size; (void)ws_size;

  float* out = (float*)d_out;
  float* p_out = out;
  float* t_out = out + (size_t)kNP * DO;
  float* a_out = out + (size_t)(kNP + kNT) * DO;

  char* base = (char*)d_ws;
  size_t off = 0;
  auto alloc = [&](size_t bytes) {
    off = (off + 255) & ~size_t(255);
    void* p = base + off;
    off += bytes;
    return p;
  };

  const int per1 = DIN * DH;  // 32768
  const int per2 = DH * DO;   // 32768

  short* t1b   = (short*)alloc((size_t)kNT * DH * 2);
  short* p1b   = (short*)alloc((size_t)kNP * DH * 2);
  short* a1b   = (short*)alloc((size_t)kNA * DH * 2);
  short* aggpt = (short*)alloc((size_t)kNT * DIN * 2);  // reused as gt later
  short* aggat = (short*)alloc((size_t)kNT * DIN * 2);
  short* aggtp = (short*)alloc((size_t)kNP * DIN * 2);
  short* aggta = (short*)alloc((size_t)kNA * DIN * 2);
  short* xpeb  = (short*)alloc((size_t)kNP * DIN * 2);
  short* xaeb  = (short*)alloc((size_t)kNA * DIN * 2);
  short* xtb   = (short*)alloc((size_t)kNT * DIN * 2);
  short* ypb   = (short*)alloc((size_t)kNP * DO * 2);
  short* yab   = (short*)alloc((size_t)kNA * DO * 2);
  short* gtpb  = (short*)alloc((size_t)kNP * DH * 2);
  short* gtab  = (short*)alloc((size_t)kNA * DH * 2);
  short* w1lb  = (short*)alloc(4 * per1 * 2);
  short* w1rb  = (short*)alloc(4 * per1 * 2);
  short* w1rcb = (short*)alloc(per1 * 2);
  short* w2lb  = (short*)alloc(4 * per2 * 2);
  short* wcb   = (short*)alloc(3 * per2 * 2);
  float* bc    = (float*)alloc(3 * DO * 4);
  float* b1ct  = (float*)alloc(DH * 4);

  int* rp_pt  = (int*)alloc((kNT + 1) * 4);
  int* rp_tp  = (int*)alloc((kNP + 1) * 4);
  int* rp_at  = (int*)alloc((kNT + 1) * 4);
  int* rp_ta  = (int*)alloc((kNA + 1) * 4);
  int* cur_pt = (int*)alloc(kNT * 4);
  int* cur_tp = (int*)alloc(kNP * 4);
  int* cur_at = (int*)alloc(kNT * 4);
  int* cur_ta = (int*)alloc(kNA * 4);
  int* col_pt = (int*)alloc(kEPT * 4);
  int* col_tp = (int*)alloc(kETP * 4);
  int* col_at = (int*)alloc(kEAT * 4);
  int* col_ta = (int*)alloc(kETA * 4);
  int* part   = (int*)alloc(1024 * 4);

  // ---- 0. bf16 converts of dense inputs ----
  cvt_bf16<true><<<cdiv(kNP * DIN / 8, 256), 256, 0, stream>>>(x_p, emb_p, xpeb, kNP * DIN / 8);
  cvt_bf16<true><<<cdiv(kNA * DIN / 8, 256), 256, 0, stream>>>(x_a, emb_a, xaeb, kNA * DIN / 8);
  cvt_bf16<false><<<cdiv(kNT * DIN / 8, 256), 256, 0, stream>>>(x_t, nullptr, xtb, kNT * DIN / 8);

  // ---- 1. weight prep (bf16, native [out][in]) ----
  scale4_bf16<<<cdiv(4 * per1, 256), 256, 0, stream>>>(W1l, w1lb, per1, 0.5f, 1.f, 0.5f, 1.f);
  scale4_bf16<<<cdiv(4 * per1, 256), 256, 0, stream>>>(W1r, w1rb, per1, 1.f, 1.f, 1.f, 1.f);
  wsum2_bf16<<<cdiv(per1, 256), 256, 0, stream>>>(W1r, W1r + 2 * per1, w1rcb, per1, 0.5f, 0.5f);
  scale4_bf16<<<cdiv(4 * per2, 256), 256, 0, stream>>>(W2l, w2lb, per2, 0.5f, 1.f, 0.5f, 1.f);
  prep_wc<<<cdiv(3 * per2, 256), 256, 0, stream>>>(Wres, W2r, bres, b2, wcb, bc);
  prep_b1ct<<<1, 256, 0, stream>>>(b1, b1ct);

  // ---- 2. CSR build x4 ----
  hipMemsetAsync(cur_pt, 0, (size_t)kNT * 4, stream);
  hipMemsetAsync(cur_tp, 0, (size_t)kNP * 4, stream);
  hipMemsetAsync(cur_at, 0, (size_t)kNT * 4, stream);
  hipMemsetAsync(cur_ta, 0, (size_t)kNA * 4, stream);
  struct CsrDesc { const int* edge; int E; int N; int* rp; int* cur; int* col; };
  CsrDesc descs[4] = {
      {e_pt, kEPT, kNT, rp_pt, cur_pt, col_pt},
      {e_tp, kETP, kNP, rp_tp, cur_tp, col_tp},
      {e_at, kEAT, kNT, rp_at, cur_at, col_at},
      {e_ta, kETA, kNA, rp_ta, cur_ta, col_ta},
  };
  for (auto& d : descs)
    hist_kernel<<<cdiv(d.E, 256), 256, 0, stream>>>(d.edge + d.E, d.E, d.cur);
  for (auto& d : descs) {
    int nb = cdiv(d.N, 256);
    scan1<<<nb, 256, 0, stream>>>(d.cur, part, d.N);
    scan2<<<1, 1024, 0, stream>>>(part, nb);
    scan3<<<nb, 256, 0, stream>>>(d.cur, part, d.rp, d.cur, d.N, d.E);
    fill_csr<<<cdiv(d.E, 256), 256, 0, stream>>>(d.edge, d.edge + d.E, d.E, d.cur, d.col);
  }

  // ---- 3. conv1 gathers (bf16 means) ----
  gather_b<16><<<cdiv(kNT, 16), 256, 0, stream>>>(xpeb, rp_pt, col_pt, aggpt, kNT);
  gather_b<16><<<cdiv(kNT, 16), 256, 0, stream>>>(xaeb, rp_at, col_at, aggat, kNT);
  gather_b<16><<<cdiv(kNP, 16), 256, 0, stream>>>(xtb, rp_tp, col_tp, aggtp, kNP);
  gather_b<16><<<cdiv(kNA, 16), 256, 0, stream>>>(xtb, rp_ta, col_ta, aggta, kNA);

  // ---- 4. conv1 GEMMs (MFMA v2) ----
  mfma_gemm<DIN, DH, 3, true, true, true, false>
      <<<cdiv(kNT, 64), 256, 0, stream>>>(aggpt, aggat, xtb, w1lb,
                                          w1lb + 2 * per1, w1rcb, b1ct, nullptr,
                                          nullptr, t1b, kNT);
  mfma_gemm<DIN, DH, 2, true, true, true, false>
      <<<cdiv(kNP, 64), 256, 0, stream>>>(aggtp, xpeb, nullptr, w1lb + 1 * per1,
                                          w1rb + 1 * per1, nullptr, b1 + 1 * DH,
                                          nullptr, nullptr, p1b, kNP);
  mfma_gemm<DIN, DH, 2, true, true, true, false>
      <<<cdiv(kNA, 64), 256, 0, stream>>>(aggta, xaeb, nullptr, w1lb + 3 * per1,
                                          w1rb + 3 * per1, nullptr, b1 + 3 * DH,
                                          nullptr, nullptr, a1b, kNA);

  // ---- 5. conv2 down-projections (transform before aggregate) ----
  mfma_gemm<DH, DO, 1, true, false, false, false>
      <<<cdiv(kNP, 128), 256, 0, stream>>>(p1b, nullptr, nullptr, w2lb, nullptr,
                                           nullptr, nullptr, nullptr, nullptr,
                                           ypb, kNP);
  mfma_gemm<DH, DO, 1, true, false, false, false>
      <<<cdiv(kNA, 128), 256, 0, stream>>>(a1b, nullptr, nullptr,
                                           w2lb + 2 * per2, nullptr, nullptr,
                                           nullptr, nullptr, nullptr, yab, kNA);

  // ---- 6. gt = mean_pt(y_p) + mean_at(y_a) (bf16), then fused t_out GEMM ----
  short* gt = aggpt;  // free after conv1-t GEMM
  gather2_b<16><<<cdiv(kNT, 16), 256, 0, stream>>>(ypb, rp_pt, col_pt, yab,
                                                   rp_at, col_at, gt, kNT);
  mfma_gemm<DH, DO, 1, false, true, false, true>
      <<<cdiv(kNT, 128), 256, 0, stream>>>(t1b, nullptr, nullptr, wcb, nullptr,
                                           nullptr, bc, gt, t_out, nullptr,
                                           kNT);

  // ---- 7. 256-d gathers of t1 ----
  gather_b<32><<<cdiv(kNP, 8), 256, 0, stream>>>(t1b, rp_tp, col_tp, gtpb, kNP);
  gather_b<32><<<cdiv(kNA, 8), 256, 0, stream>>>(t1b, rp_ta, col_ta, gtab, kNA);

  // ---- 8. p_out / a_out ----
  mfma_gemm<DH, DO, 2, false, true, false, false>
      <<<cdiv(kNP, 128), 256, 0, stream>>>(gtpb, p1b, nullptr, w2lb + 1 * per2,
                                           wcb + 1 * per2, nullptr, bc + DO,
                                           nullptr, p_out, nullptr, kNP);
  mfma_gemm<DH, DO, 2, false, true, false, false>
      <<<cdiv(kNA, 128), 256, 0, stream>>>(gtab, a1b, nullptr, w2lb + 3 * per2,
                                           wcb + 2 * per2, nullptr, bc + 2 * DO,
                                           nullptr, a_out, nullptr, kNA);
}

// Round 6
// 1101.588 us; speedup vs baseline: 1.0707x; 1.0707x over previous
//
#include <hip/hip_runtime.h>

namespace {

typedef __attribute__((ext_vector_type(8))) short short8;
typedef __attribute__((ext_vector_type(4))) float f32x4;

constexpr int kNP = 50000, kNT = 200000, kNA = 20000;
constexpr int kEPT = 1000000, kETP = 1000000, kEAT = 400000, kETA = 400000;
constexpr int DIN = 128, DH = 256, DO = 128;

__device__ __forceinline__ float bf2f(short u) {
  union { unsigned int i; float f; } c;
  c.i = ((unsigned int)(unsigned short)u) << 16;
  return c.f;
}
__device__ __forceinline__ short f2bf(float f) {
  union { float f; unsigned int i; } c;
  c.f = f;
  unsigned int r = c.i + 0x7fffu + ((c.i >> 16) & 1u);  // RNE
  return (short)(r >> 16);
}

// ---------------- converts ----------------

template <bool ADD>
__global__ __launch_bounds__(256) void cvt_bf16(const float* __restrict__ a,
                                                const float* __restrict__ b,
                                                short* __restrict__ o, int n8) {
  int g = blockIdx.x * 256 + threadIdx.x;
  if (g >= n8) return;
  const float4* a4 = reinterpret_cast<const float4*>(a);
  float4 x0 = a4[2 * g], x1 = a4[2 * g + 1];
  if constexpr (ADD) {
    const float4* b4 = reinterpret_cast<const float4*>(b);
    float4 y0 = b4[2 * g], y1 = b4[2 * g + 1];
    x0.x += y0.x; x0.y += y0.y; x0.z += y0.z; x0.w += y0.w;
    x1.x += y1.x; x1.y += y1.y; x1.z += y1.z; x1.w += y1.w;
  }
  short8 w;
  w[0] = f2bf(x0.x); w[1] = f2bf(x0.y); w[2] = f2bf(x0.z); w[3] = f2bf(x0.w);
  w[4] = f2bf(x1.x); w[5] = f2bf(x1.y); w[6] = f2bf(x1.z); w[7] = f2bf(x1.w);
  reinterpret_cast<short8*>(o)[g] = w;
}

// ---------------- weight prep (bf16, native [out][in] layout) ----------------

__global__ __launch_bounds__(256) void scale4_bf16(const float* __restrict__ in,
                                                   short* __restrict__ out,
                                                   int per, float s0, float s1,
                                                   float s2, float s3) {
  int g = blockIdx.x * 256 + threadIdx.x;
  if (g >= 4 * per) return;
  int e = g / per;
  float s = (e == 0) ? s0 : (e == 1) ? s1 : (e == 2) ? s2 : s3;
  out[g] = f2bf(in[g] * s);
}

__global__ __launch_bounds__(256) void wsum2_bf16(const float* __restrict__ in1,
                                                  const float* __restrict__ in2,
                                                  short* __restrict__ out, int n,
                                                  float sa, float sb) {
  int g = blockIdx.x * 256 + threadIdx.x;
  if (g < n) out[g] = f2bf(sa * in1[g] + sb * in2[g]);
}

// Wc[0] (track):    Wres[1] + 0.5*(W2r[0]+W2r[2])
// Wc[1] (playlist): Wres[0] + W2r[1]
// Wc[2] (artist):   Wres[2] + W2r[3];  bc likewise from bres/b2 (fp32).
__global__ __launch_bounds__(256) void prep_wc(const float* __restrict__ Wres,
                                               const float* __restrict__ W2r,
                                               const float* __restrict__ bres,
                                               const float* __restrict__ b2,
                                               short* __restrict__ Wc,
                                               float* __restrict__ bc) {
  int gid = blockIdx.x * 256 + threadIdx.x;
  const int per = DO * DH;
  if (gid < 3 * per) {
    int b = gid / per;
    int idx = gid - b * per;
    int resIdx = (b == 0) ? 1 : (b == 1) ? 0 : 2;
    float v = Wres[(size_t)resIdx * per + idx];
    if (b == 0)
      v += 0.5f * (W2r[(size_t)0 * per + idx] + W2r[(size_t)2 * per + idx]);
    else if (b == 1)
      v += W2r[(size_t)1 * per + idx];
    else
      v += W2r[(size_t)3 * per + idx];
    Wc[gid] = f2bf(v);
  }
  if (gid < 3 * DO) {
    int b = gid / DO;
    int o = gid - b * DO;
    int resIdx = (b == 0) ? 1 : (b == 1) ? 0 : 2;
    float v = bres[resIdx * DO + o];
    if (b == 0)
      v += 0.5f * (b2[0 * DO + o] + b2[2 * DO + o]);
    else if (b == 1)
      v += b2[1 * DO + o];
    else
      v += b2[3 * DO + o];
    bc[gid] = v;
  }
}

__global__ __launch_bounds__(256) void prep_b1ct(const float* __restrict__ b1,
                                                 float* __restrict__ o) {
  int g = blockIdx.x * 256 + threadIdx.x;
  if (g < DH) o[g] = 0.5f * (b1[g] + b1[2 * DH + g]);
}

// ---------------- CSR build ----------------

__global__ __launch_bounds__(256) void hist_kernel(const int* __restrict__ dst,
                                                   int E, int* __restrict__ cnt) {
  int g = blockIdx.x * 256 + threadIdx.x;
  if (g < E) atomicAdd(&cnt[dst[g]], 1);
}

__global__ __launch_bounds__(256) void scan1(const int* __restrict__ cnt,
                                             int* __restrict__ part, int N) {
  __shared__ int s[256];
  int g = blockIdx.x * 256 + threadIdx.x;
  int t = threadIdx.x;
  s[t] = (g < N) ? cnt[g] : 0;
  __syncthreads();
  for (int o = 128; o > 0; o >>= 1) {
    if (t < o) s[t] += s[t + o];
    __syncthreads();
  }
  if (t == 0) part[blockIdx.x] = s[0];
}

__global__ __launch_bounds__(1024) void scan2(int* __restrict__ part, int nb) {
  __shared__ int s[1024];
  int t = threadIdx.x;
  int v = (t < nb) ? part[t] : 0;
  s[t] = v;
  __syncthreads();
  for (int o = 1; o < 1024; o <<= 1) {
    int x = (t >= o) ? s[t - o] : 0;
    __syncthreads();
    s[t] += x;
    __syncthreads();
  }
  if (t < nb) part[t] = s[t] - v;  // exclusive
}

__global__ __launch_bounds__(256) void scan3(const int* __restrict__ cnt,
                                             const int* __restrict__ part,
                                             int* __restrict__ rp,
                                             int* __restrict__ cursor, int N,
                                             int E) {
  __shared__ int s[256];
  int g = blockIdx.x * 256 + threadIdx.x;
  int t = threadIdx.x;
  int v = (g < N) ? cnt[g] : 0;
  s[t] = v;
  __syncthreads();
  for (int o = 1; o < 256; o <<= 1) {
    int x = (t >= o) ? s[t - o] : 0;
    __syncthreads();
    s[t] += x;
    __syncthreads();
  }
  if (g < N) {
    int excl = s[t] - v + part[blockIdx.x];
    rp[g] = excl;
    cursor[g] = excl;
    if (g == N - 1) rp[N] = E;
  }
}

__global__ __launch_bounds__(256) void fill_csr(const int* __restrict__ src,
                                                const int* __restrict__ dst,
                                                int E, int* __restrict__ cursor,
                                                int* __restrict__ col) {
  int g = blockIdx.x * 256 + threadIdx.x;
  if (g < E) {
    int p = atomicAdd(&cursor[dst[g]], 1);
    col[p] = src[g];
  }
}

// ---------------- gathers (bf16 in, fp32 accumulate, bf16 out) ----------------

template <int D8>
__global__ __launch_bounds__(256) void gather_b(const short* __restrict__ X,
                                                const int* __restrict__ rp,
                                                const int* __restrict__ col,
                                                short* __restrict__ out, int N) {
  constexpr int NG = 256 / D8;
  int g = blockIdx.x * NG + (int)threadIdx.x / D8;
  int c = (int)threadIdx.x % D8;
  if (g >= N) return;
  int s = rp[g], e = rp[g + 1];
  float acc[8] = {0.f, 0.f, 0.f, 0.f, 0.f, 0.f, 0.f, 0.f};
  const short8* Xv = reinterpret_cast<const short8*>(X);
  for (int j = s; j < e; ++j) {
    short8 v = Xv[(size_t)col[j] * D8 + c];
#pragma unroll
    for (int i = 0; i < 8; ++i) acc[i] += bf2f(v[i]);
  }
  float inv = 1.0f / fmaxf((float)(e - s), 1.0f);
  short8 w;
#pragma unroll
  for (int i = 0; i < 8; ++i) w[i] = f2bf(acc[i] * inv);
  reinterpret_cast<short8*>(out)[(size_t)g * D8 + c] = w;
}

// out[g] = bf16( mean1(X1 over csr1) + mean2(X2 over csr2) )
template <int D8>
__global__ __launch_bounds__(256) void gather2_b(
    const short* __restrict__ X1, const int* __restrict__ rp1,
    const int* __restrict__ col1, const short* __restrict__ X2,
    const int* __restrict__ rp2, const int* __restrict__ col2,
    short* __restrict__ out, int N) {
  constexpr int NG = 256 / D8;
  int g = blockIdx.x * NG + (int)threadIdx.x / D8;
  int c = (int)threadIdx.x % D8;
  if (g >= N) return;
  float tot[8] = {0.f, 0.f, 0.f, 0.f, 0.f, 0.f, 0.f, 0.f};
  {
    int s = rp1[g], e = rp1[g + 1];
    float a[8] = {0.f, 0.f, 0.f, 0.f, 0.f, 0.f, 0.f, 0.f};
    const short8* Xv = reinterpret_cast<const short8*>(X1);
    for (int j = s; j < e; ++j) {
      short8 v = Xv[(size_t)col1[j] * D8 + c];
#pragma unroll
      for (int i = 0; i < 8; ++i) a[i] += bf2f(v[i]);
    }
    float inv = 1.0f / fmaxf((float)(e - s), 1.0f);
#pragma unroll
    for (int i = 0; i < 8; ++i) tot[i] += a[i] * inv;
  }
  {
    int s = rp2[g], e = rp2[g + 1];
    float a[8] = {0.f, 0.f, 0.f, 0.f, 0.f, 0.f, 0.f, 0.f};
    const short8* Xv = reinterpret_cast<const short8*>(X2);
    for (int j = s; j < e; ++j) {
      short8 v = Xv[(size_t)col2[j] * D8 + c];
#pragma unroll
      for (int i = 0; i < 8; ++i) a[i] += bf2f(v[i]);
    }
    float inv = 1.0f / fmaxf((float)(e - s), 1.0f);
#pragma unroll
    for (int i = 0; i < 8; ++i) tot[i] += a[i] * inv;
  }
  short8 w;
#pragma unroll
  for (int i = 0; i < 8; ++i) w[i] = f2bf(tot[i]);
  reinterpret_cast<short8*>(out)[(size_t)g * D8 + c] = w;
}

// ------------- MFMA GEMM v3: double-buffered global_load_lds A, B-in-regs -----
// C[n][o] = relu?( sum_a A_a[n][:] . B_a[o][:] + bias[o] + bf2f(add0[n][o]) )
// A_a: [N][K] bf16 row-major; B_a: [DOUT][K] bf16 row-major.
// Geometry: 64 rows/block, 4 waves each owning DOUT/4 cols, K chunked by 128.
template <int K, int DOUT, int NA, bool BF16OUT, bool BIAS, bool RELU,
          bool HASADD>
__global__ __launch_bounds__(256) void mfma_gemm(
    const short* __restrict__ A0, const short* __restrict__ A1,
    const short* __restrict__ A2, const short* __restrict__ B0,
    const short* __restrict__ B1, const short* __restrict__ B2,
    const float* __restrict__ bias, const short* __restrict__ add0,
    float* __restrict__ Cf, short* __restrict__ Cb, int N) {
  constexpr int WCOLS = DOUT / 4;     // cols per wave (64 or 32)
  constexpr int TN = WCOLS / 16;      // 4 or 2
  constexpr int CPK = K / 128;        // chunks per operand (1 or 2)
  constexpr int NCHUNK = NA * CPK;

  __shared__ short As[2][64 * 128];   // 2 x 16 KB, swizzled storage

  const int tid = threadIdx.x;
  const int lane = tid & 63;
  const int w = tid >> 6;
  const int lr = lane & 15;
  const int ls = lane >> 4;
  const int n0 = blockIdx.x * 64;

  const short* Ap[3] = {A0, A1, A2};
  const short* Bp[3] = {B0, B1, B2};

  // Stage chunk (operand a, k-offset kc) into As[buf] via global_load_lds.
  // LDS linear unit u (16B) holds global c8 = (u&15) ^ ((u>>4)&7) of row u>>4
  // (inverse-swizzled source => swizzled reads come out conflict-free).
  auto stage = [&](int buf, int a, int kc) {
#pragma unroll
    for (int it = 0; it < 4; ++it) {
      int u = it * 256 + w * 64 + lane;
      int row = u >> 4;
      int c8s = u & 15;
      int n = n0 + row;
      if (n >= N) n = N - 1;
      const short* g = Ap[a] + (size_t)n * K + kc + ((c8s ^ (row & 7)) << 3);
      short* l = &As[buf][(it * 256 + w * 64) * 8];
      __builtin_amdgcn_global_load_lds(
          (const __attribute__((address_space(1))) void*)g,
          (__attribute__((address_space(3))) void*)l, 16, 0, 0);
    }
  };

  f32x4 acc[4][TN] = {};

  stage(0, 0, 0);
  __syncthreads();

#pragma unroll
  for (int c = 0; c < NCHUNK; ++c) {
    const int buf = c & 1;
    const int a = c / CPK;
    const int kc = (c % CPK) * 128;
    if (c + 1 < NCHUNK)
      stage(buf ^ 1, (c + 1) / CPK, ((c + 1) % CPK) * 128);  // async prefetch

    const short* Ba = Bp[a];
#pragma unroll
    for (int kh = 0; kh < 2; ++kh) {
      short8 bfr[2][TN];
#pragma unroll
      for (int kq = 0; kq < 2; ++kq)
#pragma unroll
        for (int tn = 0; tn < TN; ++tn)
          bfr[kq][tn] = *reinterpret_cast<const short8*>(
              Ba + (size_t)(w * WCOLS + tn * 16 + lr) * K + kc +
              (kh * 2 + kq) * 32 + ls * 8);
#pragma unroll
      for (int kq = 0; kq < 2; ++kq) {
        int c8 = (kh * 2 + kq) * 4 + ls;
#pragma unroll
        for (int tm = 0; tm < 4; ++tm) {
          int row = tm * 16 + lr;
          short8 af = *reinterpret_cast<const short8*>(
              &As[buf][(row * 128 + c8 * 8) ^ ((row & 7) << 3)]);
#pragma unroll
          for (int tn = 0; tn < TN; ++tn)
            acc[tm][tn] = __builtin_amdgcn_mfma_f32_16x16x32_bf16(
                af, bfr[kq][tn], acc[tm][tn], 0, 0, 0);
        }
      }
    }
    __syncthreads();  // drains prefetch (hidden under MFMA) + guards buf reuse
  }

  // epilogue: row = n0 + tm*16 + ls*4 + r, col = w*WCOLS + tn*16 + lr
#pragma unroll
  for (int tm = 0; tm < 4; ++tm) {
#pragma unroll
    for (int tn = 0; tn < TN; ++tn) {
      int colg = w * WCOLS + tn * 16 + lr;
      float bv = 0.f;
      if constexpr (BIAS) bv = bias[colg];
#pragma unroll
      for (int r = 0; r < 4; ++r) {
        int n = n0 + tm * 16 + ls * 4 + r;
        if (n < N) {
          float v = acc[tm][tn][r] + bv;
          if constexpr (HASADD) v += bf2f(add0[(size_t)n * DOUT + colg]);
          if constexpr (RELU) v = fmaxf(v, 0.f);
          if constexpr (BF16OUT)
            Cb[(size_t)n * DOUT + colg] = f2bf(v);
          else
            Cf[(size_t)n * DOUT + colg] = v;
        }
      }
    }
  }
}

inline int cdiv(int a, int b) { return (a + b - 1) / b; }

}  // namespace

extern "C" void kernel_launch(void* const* d_in, const int* in_sizes, int n_in,
                              void* d_out, int out_size, void* d_ws,
                              size_t ws_size, hipStream_t stream) {
  const float* x_p   = (const float*)d_in[0];
  const float* x_t   = (const float*)d_in[1];
  const float* x_a   = (const float*)d_in[2];
  const float* emb_p = (const float*)d_in[3];
  const float* emb_a = (const float*)d_in[4];
  const float* W1l   = (const float*)d_in[5];
  const float* b1    = (const float*)d_in[6];
  const float* W1r   = (const float*)d_in[7];
  const float* W2l   = (const float*)d_in[8];
  const float* b2    = (const float*)d_in[9];
  const float* W2r   = (const float*)d_in[10];
  const float* Wres  = (const float*)d_in[11];
  const float* bres  = (const float*)d_in[12];
  const int* e_pt = (const int*)d_in[13];
  const int* e_tp = (const int*)d_in[14];
  const int* e_at = (const int*)d_in[15];
  const int* e_ta = (const int*)d_in[16];
  (void)in_sizes; (void)n_in; (void)out_size; (void)ws_size;

  float* out = (float*)d_out;
  float* p_out = out;
  float* t_out = out + (size_t)kNP * DO;
  float* a_out = out + (size_t)(kNP + kNT) * DO;

  char* base = (char*)d_ws;
  size_t off = 0;
  auto alloc = [&](size_t bytes) {
    off = (off + 255) & ~size_t(255);
    void* p = base + off;
    off += bytes;
    return p;
  };

  const int per1 = DIN * DH;  // 32768
  const int per2 = DH * DO;   // 32768

  short* t1b   = (short*)alloc((size_t)kNT * DH * 2);
  short* p1b   = (short*)alloc((size_t)kNP * DH * 2);
  short* a1b   = (short*)alloc((size_t)kNA * DH * 2);
  short* aggpt = (short*)alloc((size_t)kNT * DIN * 2);  // reused as gt later
  short* aggat = (short*)alloc((size_t)kNT * DIN * 2);
  short* aggtp = (short*)alloc((size_t)kNP * DIN * 2);
  short* aggta = (short*)alloc((size_t)kNA * DIN * 2);
  short* xpeb  = (short*)alloc((size_t)kNP * DIN * 2);
  short* xaeb  = (short*)alloc((size_t)kNA * DIN * 2);
  short* xtb   = (short*)alloc((size_t)kNT * DIN * 2);
  short* ypb   = (short*)alloc((size_t)kNP * DO * 2);
  short* yab   = (short*)alloc((size_t)kNA * DO * 2);
  short* gtpb  = (short*)alloc((size_t)kNP * DH * 2);
  short* gtab  = (short*)alloc((size_t)kNA * DH * 2);
  short* w1lb  = (short*)alloc(4 * per1 * 2);
  short* w1rb  = (short*)alloc(4 * per1 * 2);
  short* w1rcb = (short*)alloc(per1 * 2);
  short* w2lb  = (short*)alloc(4 * per2 * 2);
  short* wcb   = (short*)alloc(3 * per2 * 2);
  float* bc    = (float*)alloc(3 * DO * 4);
  float* b1ct  = (float*)alloc(DH * 4);

  int* rp_pt  = (int*)alloc((kNT + 1) * 4);
  int* rp_tp  = (int*)alloc((kNP + 1) * 4);
  int* rp_at  = (int*)alloc((kNT + 1) * 4);
  int* rp_ta  = (int*)alloc((kNA + 1) * 4);
  int* cur_pt = (int*)alloc(kNT * 4);
  int* cur_tp = (int*)alloc(kNP * 4);
  int* cur_at = (int*)alloc(kNT * 4);
  int* cur_ta = (int*)alloc(kNA * 4);
  int* col_pt = (int*)alloc(kEPT * 4);
  int* col_tp = (int*)alloc(kETP * 4);
  int* col_at = (int*)alloc(kEAT * 4);
  int* col_ta = (int*)alloc(kETA * 4);
  int* part   = (int*)alloc(1024 * 4);

  // ---- 0. bf16 converts of dense inputs ----
  cvt_bf16<true><<<cdiv(kNP * DIN / 8, 256), 256, 0, stream>>>(x_p, emb_p, xpeb, kNP * DIN / 8);
  cvt_bf16<true><<<cdiv(kNA * DIN / 8, 256), 256, 0, stream>>>(x_a, emb_a, xaeb, kNA * DIN / 8);
  cvt_bf16<false><<<cdiv(kNT * DIN / 8, 256), 256, 0, stream>>>(x_t, nullptr, xtb, kNT * DIN / 8);

  // ---- 1. weight prep (bf16, native [out][in]) ----
  scale4_bf16<<<cdiv(4 * per1, 256), 256, 0, stream>>>(W1l, w1lb, per1, 0.5f, 1.f, 0.5f, 1.f);
  scale4_bf16<<<cdiv(4 * per1, 256), 256, 0, stream>>>(W1r, w1rb, per1, 1.f, 1.f, 1.f, 1.f);
  wsum2_bf16<<<cdiv(per1, 256), 256, 0, stream>>>(W1r, W1r + 2 * per1, w1rcb, per1, 0.5f, 0.5f);
  scale4_bf16<<<cdiv(4 * per2, 256), 256, 0, stream>>>(W2l, w2lb, per2, 0.5f, 1.f, 0.5f, 1.f);
  prep_wc<<<cdiv(3 * per2, 256), 256, 0, stream>>>(Wres, W2r, bres, b2, wcb, bc);
  prep_b1ct<<<1, 256, 0, stream>>>(b1, b1ct);

  // ---- 2. CSR build x4 ----
  hipMemsetAsync(cur_pt, 0, (size_t)kNT * 4, stream);
  hipMemsetAsync(cur_tp, 0, (size_t)kNP * 4, stream);
  hipMemsetAsync(cur_at, 0, (size_t)kNT * 4, stream);
  hipMemsetAsync(cur_ta, 0, (size_t)kNA * 4, stream);
  struct CsrDesc { const int* edge; int E; int N; int* rp; int* cur; int* col; };
  CsrDesc descs[4] = {
      {e_pt, kEPT, kNT, rp_pt, cur_pt, col_pt},
      {e_tp, kETP, kNP, rp_tp, cur_tp, col_tp},
      {e_at, kEAT, kNT, rp_at, cur_at, col_at},
      {e_ta, kETA, kNA, rp_ta, cur_ta, col_ta},
  };
  for (auto& d : descs)
    hist_kernel<<<cdiv(d.E, 256), 256, 0, stream>>>(d.edge + d.E, d.E, d.cur);
  for (auto& d : descs) {
    int nb = cdiv(d.N, 256);
    scan1<<<nb, 256, 0, stream>>>(d.cur, part, d.N);
    scan2<<<1, 1024, 0, stream>>>(part, nb);
    scan3<<<nb, 256, 0, stream>>>(d.cur, part, d.rp, d.cur, d.N, d.E);
    fill_csr<<<cdiv(d.E, 256), 256, 0, stream>>>(d.edge, d.edge + d.E, d.E, d.cur, d.col);
  }

  // ---- 3. conv1 gathers (bf16 means) ----
  gather_b<16><<<cdiv(kNT, 16), 256, 0, stream>>>(xpeb, rp_pt, col_pt, aggpt, kNT);
  gather_b<16><<<cdiv(kNT, 16), 256, 0, stream>>>(xaeb, rp_at, col_at, aggat, kNT);
  gather_b<16><<<cdiv(kNP, 16), 256, 0, stream>>>(xtb, rp_tp, col_tp, aggtp, kNP);
  gather_b<16><<<cdiv(kNA, 16), 256, 0, stream>>>(xtb, rp_ta, col_ta, aggta, kNA);

  // ---- 4. conv1 GEMMs (MFMA v3) ----
  mfma_gemm<DIN, DH, 3, true, true, true, false>
      <<<cdiv(kNT, 64), 256, 0, stream>>>(aggpt, aggat, xtb, w1lb,
                                          w1lb + 2 * per1, w1rcb, b1ct, nullptr,
                                          nullptr, t1b, kNT);
  mfma_gemm<DIN, DH, 2, true, true, true, false>
      <<<cdiv(kNP, 64), 256, 0, stream>>>(aggtp, xpeb, nullptr, w1lb + 1 * per1,
                                          w1rb + 1 * per1, nullptr, b1 + 1 * DH,
                                          nullptr, nullptr, p1b, kNP);
  mfma_gemm<DIN, DH, 2, true, true, true, false>
      <<<cdiv(kNA, 64), 256, 0, stream>>>(aggta, xaeb, nullptr, w1lb + 3 * per1,
                                          w1rb + 3 * per1, nullptr, b1 + 3 * DH,
                                          nullptr, nullptr, a1b, kNA);

  // ---- 5. conv2 down-projections (transform before aggregate) ----
  mfma_gemm<DH, DO, 1, true, false, false, false>
      <<<cdiv(kNP, 64), 256, 0, stream>>>(p1b, nullptr, nullptr, w2lb, nullptr,
                                          nullptr, nullptr, nullptr, nullptr,
                                          ypb, kNP);
  mfma_gemm<DH, DO, 1, true, false, false, false>
      <<<cdiv(kNA, 64), 256, 0, stream>>>(a1b, nullptr, nullptr,
                                          w2lb + 2 * per2, nullptr, nullptr,
                                          nullptr, nullptr, nullptr, yab, kNA);

  // ---- 6. gt = mean_pt(y_p) + mean_at(y_a) (bf16), then fused t_out GEMM ----
  short* gt = aggpt;  // free after conv1-t GEMM
  gather2_b<16><<<cdiv(kNT, 16), 256, 0, stream>>>(ypb, rp_pt, col_pt, yab,
                                                   rp_at, col_at, gt, kNT);
  mfma_gemm<DH, DO, 1, false, true, false, true>
      <<<cdiv(kNT, 64), 256, 0, stream>>>(t1b, nullptr, nullptr, wcb, nullptr,
                                          nullptr, bc, gt, t_out, nullptr,
                                          kNT);

  // ---- 7. 256-d gathers of t1 ----
  gather_b<32><<<cdiv(kNP, 8), 256, 0, stream>>>(t1b, rp_tp, col_tp, gtpb, kNP);
  gather_b<32><<<cdiv(kNA, 8), 256, 0, stream>>>(t1b, rp_ta, col_ta, gtab, kNA);

  // ---- 8. p_out / a_out ----
  mfma_gemm<DH, DO, 2, false, true, false, false>
      <<<cdiv(kNP, 64), 256, 0, stream>>>(gtpb, p1b, nullptr, w2lb + 1 * per2,
                                          wcb + 1 * per2, nullptr, bc + DO,
                                          nullptr, p_out, nullptr, kNP);
  mfma_gemm<DH, DO, 2, false, true, false, false>
      <<<cdiv(kNA, 64), 256, 0, stream>>>(gtab, a1b, nullptr, w2lb + 3 * per2,
                                          wcb + 2 * per2, nullptr, bc + 2 * DO,
                                          nullptr, a_out, nullptr, kNA);
}

// Round 7
// 1036.328 us; speedup vs baseline: 1.1381x; 1.0630x over previous
//
#include <hip/hip_runtime.h>

namespace {

typedef __attribute__((ext_vector_type(8))) short short8;
typedef __attribute__((ext_vector_type(4))) float f32x4;

constexpr int kNP = 50000, kNT = 200000, kNA = 20000;
constexpr int kEPT = 1000000, kETP = 1000000, kEAT = 400000, kETA = 400000;
constexpr int DIN = 128, DH = 256, DO = 128;

__device__ __forceinline__ float bf2f(short u) {
  union { unsigned int i; float f; } c;
  c.i = ((unsigned int)(unsigned short)u) << 16;
  return c.f;
}
__device__ __forceinline__ short f2bf(float f) {
  union { float f; unsigned int i; } c;
  c.f = f;
  unsigned int r = c.i + 0x7fffu + ((c.i >> 16) & 1u);  // RNE
  return (short)(r >> 16);
}

// ---------------- converts ----------------

template <bool ADD>
__global__ __launch_bounds__(256) void cvt_bf16(const float* __restrict__ a,
                                                const float* __restrict__ b,
                                                short* __restrict__ o, int n8) {
  int g = blockIdx.x * 256 + threadIdx.x;
  if (g >= n8) return;
  const float4* a4 = reinterpret_cast<const float4*>(a);
  float4 x0 = a4[2 * g], x1 = a4[2 * g + 1];
  if constexpr (ADD) {
    const float4* b4 = reinterpret_cast<const float4*>(b);
    float4 y0 = b4[2 * g], y1 = b4[2 * g + 1];
    x0.x += y0.x; x0.y += y0.y; x0.z += y0.z; x0.w += y0.w;
    x1.x += y1.x; x1.y += y1.y; x1.z += y1.z; x1.w += y1.w;
  }
  short8 w;
  w[0] = f2bf(x0.x); w[1] = f2bf(x0.y); w[2] = f2bf(x0.z); w[3] = f2bf(x0.w);
  w[4] = f2bf(x1.x); w[5] = f2bf(x1.y); w[6] = f2bf(x1.z); w[7] = f2bf(x1.w);
  reinterpret_cast<short8*>(o)[g] = w;
}

// ---------------- weight prep (bf16 row-major, then fragment swizzle) --------

__global__ __launch_bounds__(256) void scale4_bf16(const float* __restrict__ in,
                                                   short* __restrict__ out,
                                                   int per, float s0, float s1,
                                                   float s2, float s3) {
  int g = blockIdx.x * 256 + threadIdx.x;
  if (g >= 4 * per) return;
  int e = g / per;
  float s = (e == 0) ? s0 : (e == 1) ? s1 : (e == 2) ? s2 : s3;
  out[g] = f2bf(in[g] * s);
}

__global__ __launch_bounds__(256) void wsum2_bf16(const float* __restrict__ in1,
                                                  const float* __restrict__ in2,
                                                  short* __restrict__ out, int n,
                                                  float sa, float sb) {
  int g = blockIdx.x * 256 + threadIdx.x;
  if (g < n) out[g] = f2bf(sa * in1[g] + sb * in2[g]);
}

// Wc[0] (track):    Wres[1] + 0.5*(W2r[0]+W2r[2])
// Wc[1] (playlist): Wres[0] + W2r[1]
// Wc[2] (artist):   Wres[2] + W2r[3];  bc likewise from bres/b2 (fp32).
__global__ __launch_bounds__(256) void prep_wc(const float* __restrict__ Wres,
                                               const float* __restrict__ W2r,
                                               const float* __restrict__ bres,
                                               const float* __restrict__ b2,
                                               short* __restrict__ Wc,
                                               float* __restrict__ bc) {
  int gid = blockIdx.x * 256 + threadIdx.x;
  const int per = DO * DH;
  if (gid < 3 * per) {
    int b = gid / per;
    int idx = gid - b * per;
    int resIdx = (b == 0) ? 1 : (b == 1) ? 0 : 2;
    float v = Wres[(size_t)resIdx * per + idx];
    if (b == 0)
      v += 0.5f * (W2r[(size_t)0 * per + idx] + W2r[(size_t)2 * per + idx]);
    else if (b == 1)
      v += W2r[(size_t)1 * per + idx];
    else
      v += W2r[(size_t)3 * per + idx];
    Wc[gid] = f2bf(v);
  }
  if (gid < 3 * DO) {
    int b = gid / DO;
    int o = gid - b * DO;
    int resIdx = (b == 0) ? 1 : (b == 1) ? 0 : 2;
    float v = bres[resIdx * DO + o];
    if (b == 0)
      v += 0.5f * (b2[0 * DO + o] + b2[2 * DO + o]);
    else if (b == 1)
      v += b2[1 * DO + o];
    else
      v += b2[3 * DO + o];
    bc[gid] = v;
  }
}

__global__ __launch_bounds__(256) void prep_b1ct(const float* __restrict__ b1,
                                                 float* __restrict__ o) {
  int g = blockIdx.x * 256 + threadIdx.x;
  if (g < DH) o[g] = 0.5f * (b1[g] + b1[2 * DH + g]);
}

// Repack bf16 [D][Kk] row-major -> fragment order [D/16][Kk/32][lane=ls*16+lr][8]
// so a wave's (colgroup, kchunk) B-fragment is one contiguous 1KB read.
// element (o,k): cg=o/16, lr=o%16, kchunk=k/32, ls=(k%32)/8, i=k%8.
__global__ __launch_bounds__(256) void swizzleB(const short* __restrict__ in,
                                                short* __restrict__ out, int M,
                                                int D, int Kk) {
  int g = blockIdx.x * 256 + threadIdx.x;
  int per8 = D * Kk / 8;
  if (g >= M * per8) return;
  int m = g / per8;
  int t = g - m * per8;
  int kch = Kk / 32;
  int cg = t / (kch * 64);
  int r1 = t - cg * kch * 64;
  int kc = r1 >> 6;
  int lane = r1 & 63;
  int ls = lane >> 4, lr = lane & 15;
  const short* src = in + (size_t)m * D * Kk + (size_t)(cg * 16 + lr) * Kk +
                     kc * 32 + ls * 8;
  short8 v = *reinterpret_cast<const short8*>(src);
  reinterpret_cast<short8*>(out + (size_t)m * D * Kk)[t] = v;
}

// ---------------- CSR build ----------------

__global__ __launch_bounds__(256) void hist_kernel(const int* __restrict__ dst,
                                                   int E, int* __restrict__ cnt) {
  int g = blockIdx.x * 256 + threadIdx.x;
  if (g < E) atomicAdd(&cnt[dst[g]], 1);
}

__global__ __launch_bounds__(256) void scan1(const int* __restrict__ cnt,
                                             int* __restrict__ part, int N) {
  __shared__ int s[256];
  int g = blockIdx.x * 256 + threadIdx.x;
  int t = threadIdx.x;
  s[t] = (g < N) ? cnt[g] : 0;
  __syncthreads();
  for (int o = 128; o > 0; o >>= 1) {
    if (t < o) s[t] += s[t + o];
    __syncthreads();
  }
  if (t == 0) part[blockIdx.x] = s[0];
}

__global__ __launch_bounds__(1024) void scan2(int* __restrict__ part, int nb) {
  __shared__ int s[1024];
  int t = threadIdx.x;
  int v = (t < nb) ? part[t] : 0;
  s[t] = v;
  __syncthreads();
  for (int o = 1; o < 1024; o <<= 1) {
    int x = (t >= o) ? s[t - o] : 0;
    __syncthreads();
    s[t] += x;
    __syncthreads();
  }
  if (t < nb) part[t] = s[t] - v;  // exclusive
}

__global__ __launch_bounds__(256) void scan3(const int* __restrict__ cnt,
                                             const int* __restrict__ part,
                                             int* __restrict__ rp,
                                             int* __restrict__ cursor, int N,
                                             int E) {
  __shared__ int s[256];
  int g = blockIdx.x * 256 + threadIdx.x;
  int t = threadIdx.x;
  int v = (g < N) ? cnt[g] : 0;
  s[t] = v;
  __syncthreads();
  for (int o = 1; o < 256; o <<= 1) {
    int x = (t >= o) ? s[t - o] : 0;
    __syncthreads();
    s[t] += x;
    __syncthreads();
  }
  if (g < N) {
    int excl = s[t] - v + part[blockIdx.x];
    rp[g] = excl;
    cursor[g] = excl;
    if (g == N - 1) rp[N] = E;
  }
}

__global__ __launch_bounds__(256) void fill_csr(const int* __restrict__ src,
                                                const int* __restrict__ dst,
                                                int E, int* __restrict__ cursor,
                                                int* __restrict__ col) {
  int g = blockIdx.x * 256 + threadIdx.x;
  if (g < E) {
    int p = atomicAdd(&cursor[dst[g]], 1);
    col[p] = src[g];
  }
}

// ---------------- gathers (bf16 in, fp32 accumulate, bf16 out) ----------------

template <int D8>
__global__ __launch_bounds__(256) void gather_b(const short* __restrict__ X,
                                                const int* __restrict__ rp,
                                                const int* __restrict__ col,
                                                short* __restrict__ out, int N) {
  constexpr int NG = 256 / D8;
  int g = blockIdx.x * NG + (int)threadIdx.x / D8;
  int c = (int)threadIdx.x % D8;
  if (g >= N) return;
  int s = rp[g], e = rp[g + 1];
  float acc[8] = {0.f, 0.f, 0.f, 0.f, 0.f, 0.f, 0.f, 0.f};
  const short8* Xv = reinterpret_cast<const short8*>(X);
  for (int j = s; j < e; ++j) {
    short8 v = Xv[(size_t)col[j] * D8 + c];
#pragma unroll
    for (int i = 0; i < 8; ++i) acc[i] += bf2f(v[i]);
  }
  float inv = 1.0f / fmaxf((float)(e - s), 1.0f);
  short8 w;
#pragma unroll
  for (int i = 0; i < 8; ++i) w[i] = f2bf(acc[i] * inv);
  reinterpret_cast<short8*>(out)[(size_t)g * D8 + c] = w;
}

// out[g] = bf16( mean1(X1 over csr1) + mean2(X2 over csr2) )
template <int D8>
__global__ __launch_bounds__(256) void gather2_b(
    const short* __restrict__ X1, const int* __restrict__ rp1,
    const int* __restrict__ col1, const short* __restrict__ X2,
    const int* __restrict__ rp2, const int* __restrict__ col2,
    short* __restrict__ out, int N) {
  constexpr int NG = 256 / D8;
  int g = blockIdx.x * NG + (int)threadIdx.x / D8;
  int c = (int)threadIdx.x % D8;
  if (g >= N) return;
  float tot[8] = {0.f, 0.f, 0.f, 0.f, 0.f, 0.f, 0.f, 0.f};
  {
    int s = rp1[g], e = rp1[g + 1];
    float a[8] = {0.f, 0.f, 0.f, 0.f, 0.f, 0.f, 0.f, 0.f};
    const short8* Xv = reinterpret_cast<const short8*>(X1);
    for (int j = s; j < e; ++j) {
      short8 v = Xv[(size_t)col1[j] * D8 + c];
#pragma unroll
      for (int i = 0; i < 8; ++i) a[i] += bf2f(v[i]);
    }
    float inv = 1.0f / fmaxf((float)(e - s), 1.0f);
#pragma unroll
    for (int i = 0; i < 8; ++i) tot[i] += a[i] * inv;
  }
  {
    int s = rp2[g], e = rp2[g + 1];
    float a[8] = {0.f, 0.f, 0.f, 0.f, 0.f, 0.f, 0.f, 0.f};
    const short8* Xv = reinterpret_cast<const short8*>(X2);
    for (int j = s; j < e; ++j) {
      short8 v = Xv[(size_t)col2[j] * D8 + c];
#pragma unroll
      for (int i = 0; i < 8; ++i) a[i] += bf2f(v[i]);
    }
    float inv = 1.0f / fmaxf((float)(e - s), 1.0f);
#pragma unroll
    for (int i = 0; i < 8; ++i) tot[i] += a[i] * inv;
  }
  short8 w;
#pragma unroll
  for (int i = 0; i < 8; ++i) w[i] = f2bf(tot[i]);
  reinterpret_cast<short8*>(out)[(size_t)g * D8 + c] = w;
}

// ------- MFMA GEMM v4: B-first issue order + coalesced fragment B ------------
// C[n][o] = relu?( sum_a A_a[n][:] . B_a[o][:] + bias[o] + bf2f(add0[n][o]) )
// A_a: [N][K] bf16 row-major; B_a: fragment-swizzled (swizzleB layout).
// Per chunk: [16 coalesced B loads] -> [A prefetch gll] -> [MFMA @vmcnt(4)] -> bar.
template <int K, int DOUT, int NA, bool BF16OUT, bool BIAS, bool RELU,
          bool HASADD>
__global__ __launch_bounds__(256) void mfma_gemm(
    const short* __restrict__ A0, const short* __restrict__ A1,
    const short* __restrict__ A2, const short* __restrict__ B0,
    const short* __restrict__ B1, const short* __restrict__ B2,
    const float* __restrict__ bias, const short* __restrict__ add0,
    float* __restrict__ Cf, short* __restrict__ Cb, int N) {
  constexpr int WCOLS = DOUT / 4;     // cols per wave (64 or 32)
  constexpr int TN = WCOLS / 16;      // 4 or 2
  constexpr int CPK = K / 128;        // chunks per operand (1 or 2)
  constexpr int NCHUNK = NA * CPK;
  constexpr int KCH = K / 32;         // k-chunks per operand row

  __shared__ short As[2][64 * 128];   // 2 x 16 KB, swizzled storage

  const int tid = threadIdx.x;
  const int lane = tid & 63;
  const int w = tid >> 6;
  const int lr = lane & 15;
  const int ls = lane >> 4;
  const int n0 = blockIdx.x * 64;

  const short* Ap[3] = {A0, A1, A2};
  const short* Bp[3] = {B0, B1, B2};

  // Stage A chunk (operand a, k-offset kc) into As[buf] via global_load_lds.
  // LDS linear unit u (16B) holds global c8 = (u&15) ^ (row&7) of row u>>4.
  auto stage = [&](int buf, int a, int kc) {
#pragma unroll
    for (int it = 0; it < 4; ++it) {
      int u = it * 256 + w * 64 + lane;
      int row = u >> 4;
      int c8s = u & 15;
      int n = n0 + row;
      if (n >= N) n = N - 1;
      const short* g = Ap[a] + (size_t)n * K + kc + ((c8s ^ (row & 7)) << 3);
      short* l = &As[buf][(it * 256 + w * 64) * 8];
      __builtin_amdgcn_global_load_lds(
          (const __attribute__((address_space(1))) void*)g,
          (__attribute__((address_space(3))) void*)l, 16, 0, 0);
    }
  };

  f32x4 acc[4][TN] = {};

  stage(0, 0, 0);
  __syncthreads();

#pragma unroll
  for (int c = 0; c < NCHUNK; ++c) {
    const int buf = c & 1;
    const int a = c / CPK;
    const int kc = (c % CPK) * 128;
    const short* Ba = Bp[a];

    // 1) all 16 B-fragment loads, coalesced (1KB per wave-load)
    short8 bfr[4][TN];
#pragma unroll
    for (int kk = 0; kk < 4; ++kk)
#pragma unroll
      for (int tn = 0; tn < TN; ++tn)
        bfr[kk][tn] = *reinterpret_cast<const short8*>(
            Ba + ((size_t)((w * TN + tn) * KCH + (kc / 32 + kk)) * 64 + lane) *
                     8);
    __builtin_amdgcn_sched_barrier(0);
    // 2) prefetch next A chunk (stays outstanding under MFMA: vmcnt(4))
    if (c + 1 < NCHUNK)
      stage(buf ^ 1, (c + 1) / CPK, ((c + 1) % CPK) * 128);
    __builtin_amdgcn_sched_barrier(0);
    // 3) MFMA phase
#pragma unroll
    for (int kk = 0; kk < 4; ++kk) {
#pragma unroll
      for (int tm = 0; tm < 4; ++tm) {
        int row = tm * 16 + lr;
        short8 af = *reinterpret_cast<const short8*>(
            &As[buf][(row * 128 + (kk * 4 + ls) * 8) ^ ((row & 7) << 3)]);
#pragma unroll
        for (int tn = 0; tn < TN; ++tn)
          acc[tm][tn] = __builtin_amdgcn_mfma_f32_16x16x32_bf16(
              af, bfr[kk][tn], acc[tm][tn], 0, 0, 0);
      }
    }
    __syncthreads();  // drains prefetch (overlapped w/ MFMA) + guards buf reuse
  }

  // epilogue: row = n0 + tm*16 + ls*4 + r, col = w*WCOLS + tn*16 + lr
#pragma unroll
  for (int tm = 0; tm < 4; ++tm) {
#pragma unroll
    for (int tn = 0; tn < TN; ++tn) {
      int colg = w * WCOLS + tn * 16 + lr;
      float bv = 0.f;
      if constexpr (BIAS) bv = bias[colg];
#pragma unroll
      for (int r = 0; r < 4; ++r) {
        int n = n0 + tm * 16 + ls * 4 + r;
        if (n < N) {
          float v = acc[tm][tn][r] + bv;
          if constexpr (HASADD) v += bf2f(add0[(size_t)n * DOUT + colg]);
          if constexpr (RELU) v = fmaxf(v, 0.f);
          if constexpr (BF16OUT)
            Cb[(size_t)n * DOUT + colg] = f2bf(v);
          else
            Cf[(size_t)n * DOUT + colg] = v;
        }
      }
    }
  }
}

inline int cdiv(int a, int b) { return (a + b - 1) / b; }

}  // namespace

extern "C" void kernel_launch(void* const* d_in, const int* in_sizes, int n_in,
                              void* d_out, int out_size, void* d_ws,
                              size_t ws_size, hipStream_t stream) {
  const float* x_p   = (const float*)d_in[0];
  const float* x_t   = (const float*)d_in[1];
  const float* x_a   = (const float*)d_in[2];
  const float* emb_p = (const float*)d_in[3];
  const float* emb_a = (const float*)d_in[4];
  const float* W1l   = (const float*)d_in[5];
  const float* b1    = (const float*)d_in[6];
  const float* W1r   = (const float*)d_in[7];
  const float* W2l   = (const float*)d_in[8];
  const float* b2    = (const float*)d_in[9];
  const float* W2r   = (const float*)d_in[10];
  const float* Wres  = (const float*)d_in[11];
  const float* bres  = (const float*)d_in[12];
  const int* e_pt = (const int*)d_in[13];
  const int* e_tp = (const int*)d_in[14];
  const int* e_at = (const int*)d_in[15];
  const int* e_ta = (const int*)d_in[16];
  (void)in_sizes; (void)n_in; (void)out_size; (void)ws_size;

  float* out = (float*)d_out;
  float* p_out = out;
  float* t_out = out + (size_t)kNP * DO;
  float* a_out = out + (size_t)(kNP + kNT) * DO;

  char* base = (char*)d_ws;
  size_t off = 0;
  auto alloc = [&](size_t bytes) {
    off = (off + 255) & ~size_t(255);
    void* p = base + off;
    off += bytes;
    return p;
  };

  const int per1 = DIN * DH;  // 32768
  const int per2 = DH * DO;   // 32768

  short* t1b   = (short*)alloc((size_t)kNT * DH * 2);
  short* p1b   = (short*)alloc((size_t)kNP * DH * 2);
  short* a1b   = (short*)alloc((size_t)kNA * DH * 2);
  short* aggpt = (short*)alloc((size_t)kNT * DIN * 2);  // reused as gt later
  short* aggat = (short*)alloc((size_t)kNT * DIN * 2);
  short* aggtp = (short*)alloc((size_t)kNP * DIN * 2);
  short* aggta = (short*)alloc((size_t)kNA * DIN * 2);
  short* xpeb  = (short*)alloc((size_t)kNP * DIN * 2);
  short* xaeb  = (short*)alloc((size_t)kNA * DIN * 2);
  short* xtb   = (short*)alloc((size_t)kNT * DIN * 2);
  short* ypb   = (short*)alloc((size_t)kNP * DO * 2);
  short* yab   = (short*)alloc((size_t)kNA * DO * 2);
  short* gtpb  = (short*)alloc((size_t)kNP * DH * 2);
  short* gtab  = (short*)alloc((size_t)kNA * DH * 2);
  // row-major bf16 weight temps
  short* w1l_rm  = (short*)alloc(4 * per1 * 2);
  short* w1r_rm  = (short*)alloc(4 * per1 * 2);
  short* w1rc_rm = (short*)alloc(per1 * 2);
  short* w2l_rm  = (short*)alloc(4 * per2 * 2);
  short* wc_rm   = (short*)alloc(3 * per2 * 2);
  // fragment-swizzled finals
  short* w1lb  = (short*)alloc(4 * per1 * 2);
  short* w1rb  = (short*)alloc(4 * per1 * 2);
  short* w1rcb = (short*)alloc(per1 * 2);
  short* w2lb  = (short*)alloc(4 * per2 * 2);
  short* wcb   = (short*)alloc(3 * per2 * 2);
  float* bc    = (float*)alloc(3 * DO * 4);
  float* b1ct  = (float*)alloc(DH * 4);

  int* rp_pt  = (int*)alloc((kNT + 1) * 4);
  int* rp_tp  = (int*)alloc((kNP + 1) * 4);
  int* rp_at  = (int*)alloc((kNT + 1) * 4);
  int* rp_ta  = (int*)alloc((kNA + 1) * 4);
  int* cur_pt = (int*)alloc(kNT * 4);
  int* cur_tp = (int*)alloc(kNP * 4);
  int* cur_at = (int*)alloc(kNT * 4);
  int* cur_ta = (int*)alloc(kNA * 4);
  int* col_pt = (int*)alloc(kEPT * 4);
  int* col_tp = (int*)alloc(kETP * 4);
  int* col_at = (int*)alloc(kEAT * 4);
  int* col_ta = (int*)alloc(kETA * 4);
  int* part   = (int*)alloc(1024 * 4);

  // ---- 0. bf16 converts of dense inputs ----
  cvt_bf16<true><<<cdiv(kNP * DIN / 8, 256), 256, 0, stream>>>(x_p, emb_p, xpeb, kNP * DIN / 8);
  cvt_bf16<true><<<cdiv(kNA * DIN / 8, 256), 256, 0, stream>>>(x_a, emb_a, xaeb, kNA * DIN / 8);
  cvt_bf16<false><<<cdiv(kNT * DIN / 8, 256), 256, 0, stream>>>(x_t, nullptr, xtb, kNT * DIN / 8);

  // ---- 1. weight prep: scale/combine (row-major bf16), then fragment swizzle --
  scale4_bf16<<<cdiv(4 * per1, 256), 256, 0, stream>>>(W1l, w1l_rm, per1, 0.5f, 1.f, 0.5f, 1.f);
  scale4_bf16<<<cdiv(4 * per1, 256), 256, 0, stream>>>(W1r, w1r_rm, per1, 1.f, 1.f, 1.f, 1.f);
  wsum2_bf16<<<cdiv(per1, 256), 256, 0, stream>>>(W1r, W1r + 2 * per1, w1rc_rm, per1, 0.5f, 0.5f);
  scale4_bf16<<<cdiv(4 * per2, 256), 256, 0, stream>>>(W2l, w2l_rm, per2, 0.5f, 1.f, 0.5f, 1.f);
  prep_wc<<<cdiv(3 * per2, 256), 256, 0, stream>>>(Wres, W2r, bres, b2, wc_rm, bc);
  prep_b1ct<<<1, 256, 0, stream>>>(b1, b1ct);
  swizzleB<<<cdiv(4 * per1 / 8, 256), 256, 0, stream>>>(w1l_rm, w1lb, 4, DH, DIN);
  swizzleB<<<cdiv(4 * per1 / 8, 256), 256, 0, stream>>>(w1r_rm, w1rb, 4, DH, DIN);
  swizzleB<<<cdiv(per1 / 8, 256), 256, 0, stream>>>(w1rc_rm, w1rcb, 1, DH, DIN);
  swizzleB<<<cdiv(4 * per2 / 8, 256), 256, 0, stream>>>(w2l_rm, w2lb, 4, DO, DH);
  swizzleB<<<cdiv(3 * per2 / 8, 256), 256, 0, stream>>>(wc_rm, wcb, 3, DO, DH);

  // ---- 2. CSR build x4 ----
  hipMemsetAsync(cur_pt, 0, (size_t)kNT * 4, stream);
  hipMemsetAsync(cur_tp, 0, (size_t)kNP * 4, stream);
  hipMemsetAsync(cur_at, 0, (size_t)kNT * 4, stream);
  hipMemsetAsync(cur_ta, 0, (size_t)kNA * 4, stream);
  struct CsrDesc { const int* edge; int E; int N; int* rp; int* cur; int* col; };
  CsrDesc descs[4] = {
      {e_pt, kEPT, kNT, rp_pt, cur_pt, col_pt},
      {e_tp, kETP, kNP, rp_tp, cur_tp, col_tp},
      {e_at, kEAT, kNT, rp_at, cur_at, col_at},
      {e_ta, kETA, kNA, rp_ta, cur_ta, col_ta},
  };
  for (auto& d : descs)
    hist_kernel<<<cdiv(d.E, 256), 256, 0, stream>>>(d.edge + d.E, d.E, d.cur);
  for (auto& d : descs) {
    int nb = cdiv(d.N, 256);
    scan1<<<nb, 256, 0, stream>>>(d.cur, part, d.N);
    scan2<<<1, 1024, 0, stream>>>(part, nb);
    scan3<<<nb, 256, 0, stream>>>(d.cur, part, d.rp, d.cur, d.N, d.E);
    fill_csr<<<cdiv(d.E, 256), 256, 0, stream>>>(d.edge, d.edge + d.E, d.E, d.cur, d.col);
  }

  // ---- 3. conv1 gathers (bf16 means) ----
  gather_b<16><<<cdiv(kNT, 16), 256, 0, stream>>>(xpeb, rp_pt, col_pt, aggpt, kNT);
  gather_b<16><<<cdiv(kNT, 16), 256, 0, stream>>>(xaeb, rp_at, col_at, aggat, kNT);
  gather_b<16><<<cdiv(kNP, 16), 256, 0, stream>>>(xtb, rp_tp, col_tp, aggtp, kNP);
  gather_b<16><<<cdiv(kNA, 16), 256, 0, stream>>>(xtb, rp_ta, col_ta, aggta, kNA);

  // ---- 4. conv1 GEMMs (MFMA v4) ----
  mfma_gemm<DIN, DH, 3, true, true, true, false>
      <<<cdiv(kNT, 64), 256, 0, stream>>>(aggpt, aggat, xtb, w1lb,
                                          w1lb + 2 * per1, w1rcb, b1ct, nullptr,
                                          nullptr, t1b, kNT);
  mfma_gemm<DIN, DH, 2, true, true, true, false>
      <<<cdiv(kNP, 64), 256, 0, stream>>>(aggtp, xpeb, nullptr, w1lb + 1 * per1,
                                          w1rb + 1 * per1, nullptr, b1 + 1 * DH,
                                          nullptr, nullptr, p1b, kNP);
  mfma_gemm<DIN, DH, 2, true, true, true, false>
      <<<cdiv(kNA, 64), 256, 0, stream>>>(aggta, xaeb, nullptr, w1lb + 3 * per1,
                                          w1rb + 3 * per1, nullptr, b1 + 3 * DH,
                                          nullptr, nullptr, a1b, kNA);

  // ---- 5. conv2 down-projections (transform before aggregate) ----
  mfma_gemm<DH, DO, 1, true, false, false, false>
      <<<cdiv(kNP, 64), 256, 0, stream>>>(p1b, nullptr, nullptr, w2lb, nullptr,
                                          nullptr, nullptr, nullptr, nullptr,
                                          ypb, kNP);
  mfma_gemm<DH, DO, 1, true, false, false, false>
      <<<cdiv(kNA, 64), 256, 0, stream>>>(a1b, nullptr, nullptr,
                                          w2lb + 2 * per2, nullptr, nullptr,
                                          nullptr, nullptr, nullptr, yab, kNA);

  // ---- 6. gt = mean_pt(y_p) + mean_at(y_a) (bf16), then fused t_out GEMM ----
  short* gt = aggpt;  // free after conv1-t GEMM
  gather2_b<16><<<cdiv(kNT, 16), 256, 0, stream>>>(ypb, rp_pt, col_pt, yab,
                                                   rp_at, col_at, gt, kNT);
  mfma_gemm<DH, DO, 1, false, true, false, true>
      <<<cdiv(kNT, 64), 256, 0, stream>>>(t1b, nullptr, nullptr, wcb, nullptr,
                                          nullptr, bc, gt, t_out, nullptr,
                                          kNT);

  // ---- 7. 256-d gathers of t1 ----
  gather_b<32><<<cdiv(kNP, 8), 256, 0, stream>>>(t1b, rp_tp, col_tp, gtpb, kNP);
  gather_b<32><<<cdiv(kNA, 8), 256, 0, stream>>>(t1b, rp_ta, col_ta, gtab, kNA);

  // ---- 8. p_out / a_out ----
  mfma_gemm<DH, DO, 2, false, true, false, false>
      <<<cdiv(kNP, 64), 256, 0, stream>>>(gtpb, p1b, nullptr, w2lb + 1 * per2,
                                          wcb + 1 * per2, nullptr, bc + DO,
                                          nullptr, p_out, nullptr, kNP);
  mfma_gemm<DH, DO, 2, false, true, false, false>
      <<<cdiv(kNA, 64), 256, 0, stream>>>(gtab, a1b, nullptr, w2lb + 3 * per2,
                                          wcb + 2 * per2, nullptr, bc + 2 * DO,
                                          nullptr, a_out, nullptr, kNA);
}

// Round 8
// 1029.177 us; speedup vs baseline: 1.1460x; 1.0069x over previous
//
#include <hip/hip_runtime.h>

namespace {

typedef __attribute__((ext_vector_type(8))) short short8;
typedef __attribute__((ext_vector_type(4))) float f32x4;

constexpr int kNP = 50000, kNT = 200000, kNA = 20000;
constexpr int kEPT = 1000000, kETP = 1000000, kEAT = 400000, kETA = 400000;
constexpr int DIN = 128, DH = 256, DO = 128;

__device__ __forceinline__ float bf2f(short u) {
  union { unsigned int i; float f; } c;
  c.i = ((unsigned int)(unsigned short)u) << 16;
  return c.f;
}
__device__ __forceinline__ short f2bf(float f) {
  union { float f; unsigned int i; } c;
  c.f = f;
  unsigned int r = c.i + 0x7fffu + ((c.i >> 16) & 1u);  // RNE
  return (short)(r >> 16);
}

// ---------------- converts ----------------

template <bool ADD>
__global__ __launch_bounds__(256) void cvt_bf16(const float* __restrict__ a,
                                                const float* __restrict__ b,
                                                short* __restrict__ o, int n8) {
  int g = blockIdx.x * 256 + threadIdx.x;
  if (g >= n8) return;
  const float4* a4 = reinterpret_cast<const float4*>(a);
  float4 x0 = a4[2 * g], x1 = a4[2 * g + 1];
  if constexpr (ADD) {
    const float4* b4 = reinterpret_cast<const float4*>(b);
    float4 y0 = b4[2 * g], y1 = b4[2 * g + 1];
    x0.x += y0.x; x0.y += y0.y; x0.z += y0.z; x0.w += y0.w;
    x1.x += y1.x; x1.y += y1.y; x1.z += y1.z; x1.w += y1.w;
  }
  short8 w;
  w[0] = f2bf(x0.x); w[1] = f2bf(x0.y); w[2] = f2bf(x0.z); w[3] = f2bf(x0.w);
  w[4] = f2bf(x1.x); w[5] = f2bf(x1.y); w[6] = f2bf(x1.z); w[7] = f2bf(x1.w);
  reinterpret_cast<short8*>(o)[g] = w;
}

// ---------------- weight prep (bf16 row-major, then fragment swizzle) --------

__global__ __launch_bounds__(256) void scale4_bf16(const float* __restrict__ in,
                                                   short* __restrict__ out,
                                                   int per, float s0, float s1,
                                                   float s2, float s3) {
  int g = blockIdx.x * 256 + threadIdx.x;
  if (g >= 4 * per) return;
  int e = g / per;
  float s = (e == 0) ? s0 : (e == 1) ? s1 : (e == 2) ? s2 : s3;
  out[g] = f2bf(in[g] * s);
}

__global__ __launch_bounds__(256) void wsum2_bf16(const float* __restrict__ in1,
                                                  const float* __restrict__ in2,
                                                  short* __restrict__ out, int n,
                                                  float sa, float sb) {
  int g = blockIdx.x * 256 + threadIdx.x;
  if (g < n) out[g] = f2bf(sa * in1[g] + sb * in2[g]);
}

// Wc[0] (track):    Wres[1] + 0.5*(W2r[0]+W2r[2])
// Wc[1] (playlist): Wres[0] + W2r[1]
// Wc[2] (artist):   Wres[2] + W2r[3];  bc likewise from bres/b2 (fp32).
__global__ __launch_bounds__(256) void prep_wc(const float* __restrict__ Wres,
                                               const float* __restrict__ W2r,
                                               const float* __restrict__ bres,
                                               const float* __restrict__ b2,
                                               short* __restrict__ Wc,
                                               float* __restrict__ bc) {
  int gid = blockIdx.x * 256 + threadIdx.x;
  const int per = DO * DH;
  if (gid < 3 * per) {
    int b = gid / per;
    int idx = gid - b * per;
    int resIdx = (b == 0) ? 1 : (b == 1) ? 0 : 2;
    float v = Wres[(size_t)resIdx * per + idx];
    if (b == 0)
      v += 0.5f * (W2r[(size_t)0 * per + idx] + W2r[(size_t)2 * per + idx]);
    else if (b == 1)
      v += W2r[(size_t)1 * per + idx];
    else
      v += W2r[(size_t)3 * per + idx];
    Wc[gid] = f2bf(v);
  }
  if (gid < 3 * DO) {
    int b = gid / DO;
    int o = gid - b * DO;
    int resIdx = (b == 0) ? 1 : (b == 1) ? 0 : 2;
    float v = bres[resIdx * DO + o];
    if (b == 0)
      v += 0.5f * (b2[0 * DO + o] + b2[2 * DO + o]);
    else if (b == 1)
      v += b2[1 * DO + o];
    else
      v += b2[3 * DO + o];
    bc[gid] = v;
  }
}

__global__ __launch_bounds__(256) void prep_b1ct(const float* __restrict__ b1,
                                                 float* __restrict__ o) {
  int g = blockIdx.x * 256 + threadIdx.x;
  if (g < DH) o[g] = 0.5f * (b1[g] + b1[2 * DH + g]);
}

// Repack bf16 [D][Kk] row-major -> fragment order [D/16][Kk/32][lane=ls*16+lr][8]
// so a wave's (colgroup, kchunk) B-fragment is one contiguous 1KB read.
__global__ __launch_bounds__(256) void swizzleB(const short* __restrict__ in,
                                                short* __restrict__ out, int M,
                                                int D, int Kk) {
  int g = blockIdx.x * 256 + threadIdx.x;
  int per8 = D * Kk / 8;
  if (g >= M * per8) return;
  int m = g / per8;
  int t = g - m * per8;
  int kch = Kk / 32;
  int cg = t / (kch * 64);
  int r1 = t - cg * kch * 64;
  int kc = r1 >> 6;
  int lane = r1 & 63;
  int ls = lane >> 4, lr = lane & 15;
  const short* src = in + (size_t)m * D * Kk + (size_t)(cg * 16 + lr) * Kk +
                     kc * 32 + ls * 8;
  short8 v = *reinterpret_cast<const short8*>(src);
  reinterpret_cast<short8*>(out + (size_t)m * D * Kk)[t] = v;
}

// ---------------- CSR build ----------------

__global__ __launch_bounds__(256) void hist_kernel(const int* __restrict__ dst,
                                                   int E, int* __restrict__ cnt) {
  int g = blockIdx.x * 256 + threadIdx.x;
  if (g < E) atomicAdd(&cnt[dst[g]], 1);
}

__global__ __launch_bounds__(256) void scan1(const int* __restrict__ cnt,
                                             int* __restrict__ part, int N) {
  __shared__ int s[256];
  int g = blockIdx.x * 256 + threadIdx.x;
  int t = threadIdx.x;
  s[t] = (g < N) ? cnt[g] : 0;
  __syncthreads();
  for (int o = 128; o > 0; o >>= 1) {
    if (t < o) s[t] += s[t + o];
    __syncthreads();
  }
  if (t == 0) part[blockIdx.x] = s[0];
}

__global__ __launch_bounds__(1024) void scan2(int* __restrict__ part, int nb) {
  __shared__ int s[1024];
  int t = threadIdx.x;
  int v = (t < nb) ? part[t] : 0;
  s[t] = v;
  __syncthreads();
  for (int o = 1; o < 1024; o <<= 1) {
    int x = (t >= o) ? s[t - o] : 0;
    __syncthreads();
    s[t] += x;
    __syncthreads();
  }
  if (t < nb) part[t] = s[t] - v;  // exclusive
}

__global__ __launch_bounds__(256) void scan3(const int* __restrict__ cnt,
                                             const int* __restrict__ part,
                                             int* __restrict__ rp,
                                             int* __restrict__ cursor, int N,
                                             int E) {
  __shared__ int s[256];
  int g = blockIdx.x * 256 + threadIdx.x;
  int t = threadIdx.x;
  int v = (g < N) ? cnt[g] : 0;
  s[t] = v;
  __syncthreads();
  for (int o = 1; o < 256; o <<= 1) {
    int x = (t >= o) ? s[t - o] : 0;
    __syncthreads();
    s[t] += x;
    __syncthreads();
  }
  if (g < N) {
    int excl = s[t] - v + part[blockIdx.x];
    rp[g] = excl;
    cursor[g] = excl;
    if (g == N - 1) rp[N] = E;
  }
}

__global__ __launch_bounds__(256) void fill_csr(const int* __restrict__ src,
                                                const int* __restrict__ dst,
                                                int E, int* __restrict__ cursor,
                                                int* __restrict__ col) {
  int g = blockIdx.x * 256 + threadIdx.x;
  if (g < E) {
    int p = atomicAdd(&cursor[dst[g]], 1);
    col[p] = src[g];
  }
}

// ---------------- gathers (bf16 in, fp32 accumulate, bf16 out) ----------------
// out[g][c] = bf16( mean_j X[col[j]*ldx8 + off8 + c] ), c in [0,D8) short8 units

template <int D8>
__global__ __launch_bounds__(256) void gather_b(const short* __restrict__ X,
                                                int ldx8, int off8,
                                                const int* __restrict__ rp,
                                                const int* __restrict__ col,
                                                short* __restrict__ out, int N) {
  constexpr int NG = 256 / D8;
  int g = blockIdx.x * NG + (int)threadIdx.x / D8;
  int c = (int)threadIdx.x % D8;
  if (g >= N) return;
  int s = rp[g], e = rp[g + 1];
  float acc[8] = {0.f, 0.f, 0.f, 0.f, 0.f, 0.f, 0.f, 0.f};
  const short8* Xv = reinterpret_cast<const short8*>(X);
  for (int j = s; j < e; ++j) {
    short8 v = Xv[(size_t)col[j] * ldx8 + off8 + c];
#pragma unroll
    for (int i = 0; i < 8; ++i) acc[i] += bf2f(v[i]);
  }
  float inv = 1.0f / fmaxf((float)(e - s), 1.0f);
  short8 w;
#pragma unroll
  for (int i = 0; i < 8; ++i) w[i] = f2bf(acc[i] * inv);
  reinterpret_cast<short8*>(out)[(size_t)g * D8 + c] = w;
}

// out[g] = bf16( mean1(X1 over csr1) + mean2(X2 over csr2) )
template <int D8>
__global__ __launch_bounds__(256) void gather2_b(
    const short* __restrict__ X1, const int* __restrict__ rp1,
    const int* __restrict__ col1, const short* __restrict__ X2,
    const int* __restrict__ rp2, const int* __restrict__ col2,
    short* __restrict__ out, int N) {
  constexpr int NG = 256 / D8;
  int g = blockIdx.x * NG + (int)threadIdx.x / D8;
  int c = (int)threadIdx.x % D8;
  if (g >= N) return;
  float tot[8] = {0.f, 0.f, 0.f, 0.f, 0.f, 0.f, 0.f, 0.f};
  {
    int s = rp1[g], e = rp1[g + 1];
    float a[8] = {0.f, 0.f, 0.f, 0.f, 0.f, 0.f, 0.f, 0.f};
    const short8* Xv = reinterpret_cast<const short8*>(X1);
    for (int j = s; j < e; ++j) {
      short8 v = Xv[(size_t)col1[j] * D8 + c];
#pragma unroll
      for (int i = 0; i < 8; ++i) a[i] += bf2f(v[i]);
    }
    float inv = 1.0f / fmaxf((float)(e - s), 1.0f);
#pragma unroll
    for (int i = 0; i < 8; ++i) tot[i] += a[i] * inv;
  }
  {
    int s = rp2[g], e = rp2[g + 1];
    float a[8] = {0.f, 0.f, 0.f, 0.f, 0.f, 0.f, 0.f, 0.f};
    const short8* Xv = reinterpret_cast<const short8*>(X2);
    for (int j = s; j < e; ++j) {
      short8 v = Xv[(size_t)col2[j] * D8 + c];
#pragma unroll
      for (int i = 0; i < 8; ++i) a[i] += bf2f(v[i]);
    }
    float inv = 1.0f / fmaxf((float)(e - s), 1.0f);
#pragma unroll
    for (int i = 0; i < 8; ++i) tot[i] += a[i] * inv;
  }
  short8 w;
#pragma unroll
  for (int i = 0; i < 8; ++i) w[i] = f2bf(tot[i]);
  reinterpret_cast<short8*>(out)[(size_t)g * D8 + c] = w;
}

// ------- MFMA GEMM v5: 8 waves, small per-wave tile, B-first counted vmcnt ---
// C[n][o] = relu?( sum_a A_a[n][:] . B_a[o][:] + bias[o] + bf2f(add0[n][o]) )
// A_a: [N][K] bf16 row-major; B_a: fragment-swizzled (swizzleB layout).
template <int K, int DOUT, int NA, bool BF16OUT, bool BIAS, bool RELU,
          bool HASADD>
__global__ __launch_bounds__(512, 4) void mfma_gemm(
    const short* __restrict__ A0, const short* __restrict__ A1,
    const short* __restrict__ A2, const short* __restrict__ B0,
    const short* __restrict__ B1, const short* __restrict__ B2,
    const float* __restrict__ bias, const short* __restrict__ add0,
    float* __restrict__ Cf, short* __restrict__ Cb, int N) {
  constexpr int WC = (DOUT == 256) ? 8 : 4;  // col-waves
  constexpr int WR = 8 / WC;                 // row-panels
  constexpr int TM = 4 / WR;                 // 16-row tiles per wave
  constexpr int TN = DOUT / WC / 16;         // 2
  constexpr int CPK = K / 128;
  constexpr int NCHUNK = NA * CPK;
  constexpr int KCH = K / 32;

  __shared__ short As[2][64 * 128];  // 2 x 16 KB, swizzled storage

  const int tid = threadIdx.x;
  const int lane = tid & 63;
  const int w = tid >> 6;  // 0..7
  const int wc = w % WC;
  const int wr = w / WC;
  const int lr = lane & 15;
  const int ls = lane >> 4;
  const int n0 = blockIdx.x * 64;

  const short* Ap[3] = {A0, A1, A2};
  const short* Bp[3] = {B0, B1, B2};

  // Stage A chunk into As[buf] (linear dest, inverse-swizzled global source).
  auto stage = [&](int buf, int a, int kc) {
#pragma unroll
    for (int it = 0; it < 2; ++it) {
      int u = it * 512 + w * 64 + lane;
      int row = u >> 4;
      int c8s = u & 15;
      int n = n0 + row;
      if (n >= N) n = N - 1;
      const short* g = Ap[a] + (size_t)n * K + kc + ((c8s ^ (row & 7)) << 3);
      short* l = &As[buf][(it * 512 + w * 64) * 8];
      __builtin_amdgcn_global_load_lds(
          (const __attribute__((address_space(1))) void*)g,
          (__attribute__((address_space(3))) void*)l, 16, 0, 0);
    }
  };

  f32x4 acc[TM][TN] = {};

  stage(0, 0, 0);
  __syncthreads();

#pragma unroll
  for (int c = 0; c < NCHUNK; ++c) {
    const int buf = c & 1;
    const int a = c / CPK;
    const int kc32 = (c % CPK) * 4;  // k-chunk base (units of 32)
    const short* Ba = Bp[a];

    // 1) all B-fragment loads (coalesced 1KB wave reads)
    short8 bfr[4][TN];
#pragma unroll
    for (int kk = 0; kk < 4; ++kk)
#pragma unroll
      for (int tn = 0; tn < TN; ++tn)
        bfr[kk][tn] = *reinterpret_cast<const short8*>(
            Ba +
            ((size_t)((wc * TN + tn) * KCH + kc32 + kk) * 64 + lane) * 8);
    __builtin_amdgcn_sched_barrier(0);
    // 2) prefetch next A chunk (stays outstanding under MFMA)
    if (c + 1 < NCHUNK)
      stage(buf ^ 1, (c + 1) / CPK, ((c + 1) % CPK) * 128);
    __builtin_amdgcn_sched_barrier(0);
    // 3) MFMA phase
#pragma unroll
    for (int kk = 0; kk < 4; ++kk) {
#pragma unroll
      for (int tm = 0; tm < TM; ++tm) {
        int row = wr * TM * 16 + tm * 16 + lr;
        short8 af = *reinterpret_cast<const short8*>(
            &As[buf][(row * 128 + (kk * 4 + ls) * 8) ^ ((row & 7) << 3)]);
#pragma unroll
        for (int tn = 0; tn < TN; ++tn)
          acc[tm][tn] = __builtin_amdgcn_mfma_f32_16x16x32_bf16(
              af, bfr[kk][tn], acc[tm][tn], 0, 0, 0);
      }
    }
    __syncthreads();
  }

  // epilogue
#pragma unroll
  for (int tm = 0; tm < TM; ++tm) {
#pragma unroll
    for (int tn = 0; tn < TN; ++tn) {
      int colg = wc * TN * 16 + tn * 16 + lr;
      float bv = 0.f;
      if constexpr (BIAS) bv = bias[colg];
#pragma unroll
      for (int r = 0; r < 4; ++r) {
        int n = n0 + wr * TM * 16 + tm * 16 + ls * 4 + r;
        if (n < N) {
          float v = acc[tm][tn][r] + bv;
          if constexpr (HASADD) v += bf2f(add0[(size_t)n * DOUT + colg]);
          if constexpr (RELU) v = fmaxf(v, 0.f);
          if constexpr (BF16OUT)
            Cb[(size_t)n * DOUT + colg] = f2bf(v);
          else
            Cf[(size_t)n * DOUT + colg] = v;
        }
      }
    }
  }
}

inline int cdiv(int a, int b) { return (a + b - 1) / b; }

}  // namespace

extern "C" void kernel_launch(void* const* d_in, const int* in_sizes, int n_in,
                              void* d_out, int out_size, void* d_ws,
                              size_t ws_size, hipStream_t stream) {
  const float* x_p   = (const float*)d_in[0];
  const float* x_t   = (const float*)d_in[1];
  const float* x_a   = (const float*)d_in[2];
  const float* emb_p = (const float*)d_in[3];
  const float* emb_a = (const float*)d_in[4];
  const float* W1l   = (const float*)d_in[5];
  const float* b1    = (const float*)d_in[6];
  const float* W1r   = (const float*)d_in[7];
  const float* W2l   = (const float*)d_in[8];
  const float* b2    = (const float*)d_in[9];
  const float* W2r   = (const float*)d_in[10];
  const float* Wres  = (const float*)d_in[11];
  const float* bres  = (const float*)d_in[12];
  const int* e_pt = (const int*)d_in[13];
  const int* e_tp = (const int*)d_in[14];
  const int* e_at = (const int*)d_in[15];
  const int* e_ta = (const int*)d_in[16];
  (void)in_sizes; (void)n_in; (void)out_size; (void)ws_size;

  float* out = (float*)d_out;
  float* p_out = out;
  float* t_out = out + (size_t)kNP * DO;
  float* a_out = out + (size_t)(kNP + kNT) * DO;

  char* base = (char*)d_ws;
  size_t off = 0;
  auto alloc = [&](size_t bytes) {
    off = (off + 255) & ~size_t(255);
    void* p = base + off;
    off += bytes;
    return p;
  };

  const int per1 = DIN * DH;  // 32768
  const int per2 = DH * DO;   // 32768

  short* t1b   = (short*)alloc((size_t)kNT * DH * 2);
  short* p1b   = (short*)alloc((size_t)kNP * DH * 2);
  short* a1b   = (short*)alloc((size_t)kNA * DH * 2);
  short* aggpt = (short*)alloc((size_t)kNT * DIN * 2);  // later: gt, then ypab
  short* aggat = (short*)alloc((size_t)kNT * DIN * 2);  // (ypab spans these)
  short* aggtp = (short*)alloc((size_t)kNP * DIN * 2);
  short* aggta = (short*)alloc((size_t)kNA * DIN * 2);
  short* xpeb  = (short*)alloc((size_t)kNP * DIN * 2);
  short* xaeb  = (short*)alloc((size_t)kNA * DIN * 2);
  short* xtb   = (short*)alloc((size_t)kNT * DIN * 2);
  short* ypb   = (short*)alloc((size_t)kNP * DO * 2);
  short* yab   = (short*)alloc((size_t)kNA * DO * 2);
  short* g_tp  = (short*)alloc((size_t)kNP * DO * 2);
  short* g_ta  = (short*)alloc((size_t)kNA * DO * 2);
  // row-major bf16 weight temps
  short* w1l_rm  = (short*)alloc(4 * per1 * 2);
  short* w1r_rm  = (short*)alloc(4 * per1 * 2);
  short* w1rc_rm = (short*)alloc(per1 * 2);
  short* w2l_rm  = (short*)alloc(4 * per2 * 2);
  short* wc_rm   = (short*)alloc(3 * per2 * 2);
  // fragment-swizzled finals
  short* w1lb   = (short*)alloc(4 * per1 * 2);
  short* w1rb   = (short*)alloc(4 * per1 * 2);
  short* w1rcb  = (short*)alloc(per1 * 2);
  short* w2lb   = (short*)alloc(4 * per2 * 2);
  short* wcb    = (short*)alloc(3 * per2 * 2);
  short* w2lpab = (short*)alloc(2 * per2 * 2);  // [W2l1;W2l3] stacked, 256x256
  float* bc     = (float*)alloc(3 * DO * 4);
  float* b1ct   = (float*)alloc(DH * 4);

  int* rp_pt  = (int*)alloc((kNT + 1) * 4);
  int* rp_tp  = (int*)alloc((kNP + 1) * 4);
  int* rp_at  = (int*)alloc((kNT + 1) * 4);
  int* rp_ta  = (int*)alloc((kNA + 1) * 4);
  int* cur_pt = (int*)alloc(kNT * 4);
  int* cur_tp = (int*)alloc(kNP * 4);
  int* cur_at = (int*)alloc(kNT * 4);
  int* cur_ta = (int*)alloc(kNA * 4);
  int* col_pt = (int*)alloc(kEPT * 4);
  int* col_tp = (int*)alloc(kETP * 4);
  int* col_at = (int*)alloc(kEAT * 4);
  int* col_ta = (int*)alloc(kETA * 4);
  int* part   = (int*)alloc(1024 * 4);

  // ---- 0. bf16 converts of dense inputs ----
  cvt_bf16<true><<<cdiv(kNP * DIN / 8, 256), 256, 0, stream>>>(x_p, emb_p, xpeb, kNP * DIN / 8);
  cvt_bf16<true><<<cdiv(kNA * DIN / 8, 256), 256, 0, stream>>>(x_a, emb_a, xaeb, kNA * DIN / 8);
  cvt_bf16<false><<<cdiv(kNT * DIN / 8, 256), 256, 0, stream>>>(x_t, nullptr, xtb, kNT * DIN / 8);

  // ---- 1. weight prep: scale/combine (row-major bf16), then fragment swizzle --
  scale4_bf16<<<cdiv(4 * per1, 256), 256, 0, stream>>>(W1l, w1l_rm, per1, 0.5f, 1.f, 0.5f, 1.f);
  scale4_bf16<<<cdiv(4 * per1, 256), 256, 0, stream>>>(W1r, w1r_rm, per1, 1.f, 1.f, 1.f, 1.f);
  wsum2_bf16<<<cdiv(per1, 256), 256, 0, stream>>>(W1r, W1r + 2 * per1, w1rc_rm, per1, 0.5f, 0.5f);
  scale4_bf16<<<cdiv(4 * per2, 256), 256, 0, stream>>>(W2l, w2l_rm, per2, 0.5f, 1.f, 0.5f, 1.f);
  prep_wc<<<cdiv(3 * per2, 256), 256, 0, stream>>>(Wres, W2r, bres, b2, wc_rm, bc);
  prep_b1ct<<<1, 256, 0, stream>>>(b1, b1ct);
  swizzleB<<<cdiv(4 * per1 / 8, 256), 256, 0, stream>>>(w1l_rm, w1lb, 4, DH, DIN);
  swizzleB<<<cdiv(4 * per1 / 8, 256), 256, 0, stream>>>(w1r_rm, w1rb, 4, DH, DIN);
  swizzleB<<<cdiv(per1 / 8, 256), 256, 0, stream>>>(w1rc_rm, w1rcb, 1, DH, DIN);
  swizzleB<<<cdiv(4 * per2 / 8, 256), 256, 0, stream>>>(w2l_rm, w2lb, 4, DO, DH);
  swizzleB<<<cdiv(3 * per2 / 8, 256), 256, 0, stream>>>(wc_rm, wcb, 3, DO, DH);
  // stacked [W2l1;W2l3] fragment layout: cg-major => halves are contiguous
  swizzleB<<<cdiv(per2 / 8, 256), 256, 0, stream>>>(w2l_rm + per2, w2lpab, 1, DO, DH);
  swizzleB<<<cdiv(per2 / 8, 256), 256, 0, stream>>>(w2l_rm + 3 * per2, w2lpab + per2, 1, DO, DH);

  // ---- 2. CSR build x4 ----
  hipMemsetAsync(cur_pt, 0, (size_t)kNT * 4, stream);
  hipMemsetAsync(cur_tp, 0, (size_t)kNP * 4, stream);
  hipMemsetAsync(cur_at, 0, (size_t)kNT * 4, stream);
  hipMemsetAsync(cur_ta, 0, (size_t)kNA * 4, stream);
  struct CsrDesc { const int* edge; int E; int N; int* rp; int* cur; int* col; };
  CsrDesc descs[4] = {
      {e_pt, kEPT, kNT, rp_pt, cur_pt, col_pt},
      {e_tp, kETP, kNP, rp_tp, cur_tp, col_tp},
      {e_at, kEAT, kNT, rp_at, cur_at, col_at},
      {e_ta, kETA, kNA, rp_ta, cur_ta, col_ta},
  };
  for (auto& d : descs)
    hist_kernel<<<cdiv(d.E, 256), 256, 0, stream>>>(d.edge + d.E, d.E, d.cur);
  for (auto& d : descs) {
    int nb = cdiv(d.N, 256);
    scan1<<<nb, 256, 0, stream>>>(d.cur, part, d.N);
    scan2<<<1, 1024, 0, stream>>>(part, nb);
    scan3<<<nb, 256, 0, stream>>>(d.cur, part, d.rp, d.cur, d.N, d.E);
    fill_csr<<<cdiv(d.E, 256), 256, 0, stream>>>(d.edge, d.edge + d.E, d.E, d.cur, d.col);
  }

  // ---- 3. conv1 gathers (bf16 means) ----
  gather_b<16><<<cdiv(kNT, 16), 256, 0, stream>>>(xpeb, 16, 0, rp_pt, col_pt, aggpt, kNT);
  gather_b<16><<<cdiv(kNT, 16), 256, 0, stream>>>(xaeb, 16, 0, rp_at, col_at, aggat, kNT);
  gather_b<16><<<cdiv(kNP, 16), 256, 0, stream>>>(xtb, 16, 0, rp_tp, col_tp, aggtp, kNP);
  gather_b<16><<<cdiv(kNA, 16), 256, 0, stream>>>(xtb, 16, 0, rp_ta, col_ta, aggta, kNA);

  // ---- 4. conv1 GEMMs ----
  mfma_gemm<DIN, DH, 3, true, true, true, false>
      <<<cdiv(kNT, 64), 512, 0, stream>>>(aggpt, aggat, xtb, w1lb,
                                          w1lb + 2 * per1, w1rcb, b1ct, nullptr,
                                          nullptr, t1b, kNT);
  mfma_gemm<DIN, DH, 2, true, true, true, false>
      <<<cdiv(kNP, 64), 512, 0, stream>>>(aggtp, xpeb, nullptr, w1lb + 1 * per1,
                                          w1rb + 1 * per1, nullptr, b1 + 1 * DH,
                                          nullptr, nullptr, p1b, kNP);
  mfma_gemm<DIN, DH, 2, true, true, true, false>
      <<<cdiv(kNA, 64), 512, 0, stream>>>(aggta, xaeb, nullptr, w1lb + 3 * per1,
                                          w1rb + 3 * per1, nullptr, b1 + 3 * DH,
                                          nullptr, nullptr, a1b, kNA);

  // ---- 5. conv2 down-projections for the track terms ----
  mfma_gemm<DH, DO, 1, true, false, false, false>
      <<<cdiv(kNP, 64), 512, 0, stream>>>(p1b, nullptr, nullptr, w2lb, nullptr,
                                          nullptr, nullptr, nullptr, nullptr,
                                          ypb, kNP);
  mfma_gemm<DH, DO, 1, true, false, false, false>
      <<<cdiv(kNA, 64), 512, 0, stream>>>(a1b, nullptr, nullptr,
                                          w2lb + 2 * per2, nullptr, nullptr,
                                          nullptr, nullptr, nullptr, yab, kNA);

  // ---- 6. gt = mean_pt(y_p) + mean_at(y_a), fused t_out GEMM ----
  short* gt = aggpt;  // free after conv1-t GEMM
  gather2_b<16><<<cdiv(kNT, 16), 256, 0, stream>>>(ypb, rp_pt, col_pt, yab,
                                                   rp_at, col_at, gt, kNT);
  mfma_gemm<DH, DO, 1, false, true, false, true>
      <<<cdiv(kNT, 64), 512, 0, stream>>>(t1b, nullptr, nullptr, wcb, nullptr,
                                          nullptr, bc, gt, t_out, nullptr,
                                          kNT);

  // ---- 7. y_pa = t1 @ [W2l1;W2l3]^T (transform before aggregate) ----
  short* ypab = aggpt;  // spans aggpt..aggta (120.3 MB region >= 102.4 MB)
  mfma_gemm<DH, 256, 1, true, false, false, false>
      <<<cdiv(kNT, 64), 512, 0, stream>>>(t1b, nullptr, nullptr, w2lpab,
                                          nullptr, nullptr, nullptr, nullptr,
                                          nullptr, ypab, kNT);

  // ---- 8. 128-d gathers in output space ----
  gather_b<16><<<cdiv(kNP, 16), 256, 0, stream>>>(ypab, 32, 0, rp_tp, col_tp, g_tp, kNP);
  gather_b<16><<<cdiv(kNA, 16), 256, 0, stream>>>(ypab, 32, 16, rp_ta, col_ta, g_ta, kNA);

  // ---- 9. p_out / a_out (NA=1 + fused gathered add) ----
  mfma_gemm<DH, DO, 1, false, true, false, true>
      <<<cdiv(kNP, 64), 512, 0, stream>>>(p1b, nullptr, nullptr, wcb + per2,
                                          nullptr, nullptr, bc + DO, g_tp,
                                          p_out, nullptr, kNP);
  mfma_gemm<DH, DO, 1, false, true, false, true>
      <<<cdiv(kNA, 64), 512, 0, stream>>>(a1b, nullptr, nullptr,
                                          wcb + 2 * per2, nullptr, nullptr,
                                          bc + 2 * DO, g_ta, a_out, nullptr,
                                          kNA);
}

// Round 9
// 905.089 us; speedup vs baseline: 1.3031x; 1.1371x over previous
//
#include <hip/hip_runtime.h>

namespace {

typedef __attribute__((ext_vector_type(8))) short short8;
typedef __attribute__((ext_vector_type(4))) float f32x4;

constexpr int kNP = 50000, kNT = 200000, kNA = 20000;
constexpr int kEPT = 1000000, kETP = 1000000, kEAT = 400000, kETA = 400000;
constexpr int DIN = 128, DH = 256, DO = 128;
constexpr int per1 = DIN * DH;  // 32768
constexpr int per2 = DH * DO;   // 32768

__device__ __forceinline__ float bf2f(short u) {
  union { unsigned int i; float f; } c;
  c.i = ((unsigned int)(unsigned short)u) << 16;
  return c.f;
}
__device__ __forceinline__ short f2bf(float f) {
  union { float f; unsigned int i; } c;
  c.f = f;
  unsigned int r = c.i + 0x7fffu + ((c.i >> 16) & 1u);  // RNE
  return (short)(r >> 16);
}

inline int cdiv(int a, int b) { return (a + b - 1) / b; }
constexpr int ccdiv(int a, int b) { return (a + b - 1) / b; }

// ---------------- fused convert: xpe, xae, xt -> bf16 ----------------

__global__ __launch_bounds__(256) void cvt_all(
    const float* __restrict__ x_p, const float* __restrict__ emb_p,
    short* __restrict__ xpeb, const float* __restrict__ x_a,
    const float* __restrict__ emb_a, short* __restrict__ xaeb,
    const float* __restrict__ x_t, short* __restrict__ xtb) {
  constexpr int N0 = kNP * DIN / 8;
  constexpr int N1 = N0 + kNA * DIN / 8;
  constexpr int N2 = N1 + kNT * DIN / 8;
  int g = blockIdx.x * 256 + threadIdx.x;
  const float* a;
  const float* b = nullptr;
  short* o;
  int i;
  if (g < N0) { a = x_p; b = emb_p; o = xpeb; i = g; }
  else if (g < N1) { a = x_a; b = emb_a; o = xaeb; i = g - N0; }
  else if (g < N2) { a = x_t; o = xtb; i = g - N1; }
  else return;
  const float4* a4 = reinterpret_cast<const float4*>(a);
  float4 x0 = a4[2 * i], x1 = a4[2 * i + 1];
  if (b != nullptr) {
    const float4* b4 = reinterpret_cast<const float4*>(b);
    float4 y0 = b4[2 * i], y1 = b4[2 * i + 1];
    x0.x += y0.x; x0.y += y0.y; x0.z += y0.z; x0.w += y0.w;
    x1.x += y1.x; x1.y += y1.y; x1.z += y1.z; x1.w += y1.w;
  }
  short8 w;
  w[0] = f2bf(x0.x); w[1] = f2bf(x0.y); w[2] = f2bf(x0.z); w[3] = f2bf(x0.w);
  w[4] = f2bf(x1.x); w[5] = f2bf(x1.y); w[6] = f2bf(x1.z); w[7] = f2bf(x1.w);
  reinterpret_cast<short8*>(o)[i] = w;
}

// ---------------- fused weight prep (row-major bf16 + fp32 biases) -----------

__global__ __launch_bounds__(256) void prep_all(
    const float* __restrict__ W1l, const float* __restrict__ W1r,
    const float* __restrict__ W2l, const float* __restrict__ Wres,
    const float* __restrict__ W2r, const float* __restrict__ bres,
    const float* __restrict__ b2, const float* __restrict__ b1,
    short* __restrict__ w1l_rm, short* __restrict__ w1r_rm,
    short* __restrict__ w1rc_rm, short* __restrict__ w2l_rm,
    short* __restrict__ wc_rm, float* __restrict__ bc,
    float* __restrict__ b1ct) {
  constexpr int P0 = 4 * per1;
  constexpr int P1 = P0 + 4 * per1;
  constexpr int P2 = P1 + per1;
  constexpr int P3 = P2 + 4 * per2;
  constexpr int P4 = P3 + 3 * per2;
  constexpr int P5 = P4 + DH;
  int g = blockIdx.x * 256 + threadIdx.x;
  if (g < P0) {  // w1l scaled (0.5,1,0.5,1)
    int e = g / per1;
    float s = (e == 0 || e == 2) ? 0.5f : 1.0f;
    w1l_rm[g] = f2bf(W1l[g] * s);
  } else if (g < P1) {  // w1r plain cvt
    int l = g - P0;
    w1r_rm[l] = f2bf(W1r[l]);
  } else if (g < P2) {  // w1rc = 0.5*(W1r0+W1r2)
    int l = g - P1;
    w1rc_rm[l] = f2bf(0.5f * (W1r[l] + W1r[2 * per1 + l]));
  } else if (g < P3) {  // w2l scaled (0.5,1,0.5,1)
    int l = g - P2;
    int e = l / per2;
    float s = (e == 0 || e == 2) ? 0.5f : 1.0f;
    w2l_rm[l] = f2bf(W2l[l] * s);
  } else if (g < P4) {  // wc (+bc)
    int l = g - P3;
    {
      int b = l / per2;
      int idx = l - b * per2;
      int resIdx = (b == 0) ? 1 : (b == 1) ? 0 : 2;
      float v = Wres[(size_t)resIdx * per2 + idx];
      if (b == 0)
        v += 0.5f * (W2r[idx] + W2r[(size_t)2 * per2 + idx]);
      else if (b == 1)
        v += W2r[(size_t)1 * per2 + idx];
      else
        v += W2r[(size_t)3 * per2 + idx];
      wc_rm[l] = f2bf(v);
    }
    if (l < 3 * DO) {
      int b = l / DO;
      int o = l - b * DO;
      int resIdx = (b == 0) ? 1 : (b == 1) ? 0 : 2;
      float v = bres[resIdx * DO + o];
      if (b == 0)
        v += 0.5f * (b2[0 * DO + o] + b2[2 * DO + o]);
      else if (b == 1)
        v += b2[1 * DO + o];
      else
        v += b2[3 * DO + o];
      bc[l] = v;
    }
  } else if (g < P5) {  // b1ct
    int l = g - P4;
    b1ct[l] = 0.5f * (b1[l] + b1[2 * DH + l]);
  }
}

// ---------------- fragment swizzle (all weights, one launch) ------------------
// bf16 [D][Kk] row-major -> [D/16][Kk/32][lane=ls*16+lr][8]

__device__ __forceinline__ void swz1(const short* __restrict__ in,
                                     short* __restrict__ out, int t, int D,
                                     int Kk) {
  int kch = Kk / 32;
  int per8 = D * Kk / 8;
  int m = t / per8;
  int tt = t - m * per8;
  int cg = tt / (kch * 64);
  int r1 = tt - cg * kch * 64;
  int kc = r1 >> 6;
  int lane = r1 & 63;
  int ls = lane >> 4, lr = lane & 15;
  const short* src = in + (size_t)m * D * Kk + (size_t)(cg * 16 + lr) * Kk +
                     kc * 32 + ls * 8;
  short8 v = *reinterpret_cast<const short8*>(src);
  reinterpret_cast<short8*>(out + (size_t)m * D * Kk)[tt] = v;
}

__global__ __launch_bounds__(256) void swizzle_all(
    const short* __restrict__ w1l_rm, short* __restrict__ w1lb,
    const short* __restrict__ w1r_rm, short* __restrict__ w1rb,
    const short* __restrict__ w1rc_rm, short* __restrict__ w1rcb,
    const short* __restrict__ w2l_rm, short* __restrict__ w2lb,
    const short* __restrict__ wc_rm, short* __restrict__ wcb,
    short* __restrict__ w2lpab) {
  constexpr int S0 = 4 * per1 / 8;         // 16384
  constexpr int S1 = S0 + 4 * per1 / 8;    // 32768
  constexpr int S2 = S1 + per1 / 8;        // 36864
  constexpr int S3 = S2 + 4 * per2 / 8;    // 53248
  constexpr int S4 = S3 + 3 * per2 / 8;    // 65536
  constexpr int S5 = S4 + per2 / 8;        // 69632
  constexpr int S6 = S5 + per2 / 8;        // 73728
  int g = blockIdx.x * 256 + threadIdx.x;
  if (g < S0) swz1(w1l_rm, w1lb, g, DH, DIN);
  else if (g < S1) swz1(w1r_rm, w1rb, g - S0, DH, DIN);
  else if (g < S2) swz1(w1rc_rm, w1rcb, g - S1, DH, DIN);
  else if (g < S3) swz1(w2l_rm, w2lb, g - S2, DO, DH);
  else if (g < S4) swz1(wc_rm, wcb, g - S3, DO, DH);
  else if (g < S5) swz1(w2l_rm + per2, w2lpab, g - S4, DO, DH);
  else if (g < S6) swz1(w2l_rm + 3 * per2, w2lpab + per2, g - S5, DO, DH);
}

// ---------------- CSR build (batched over the 4 edge types) ------------------

__global__ __launch_bounds__(256) void hist_all(
    const int* __restrict__ e_pt, const int* __restrict__ e_tp,
    const int* __restrict__ e_at, const int* __restrict__ e_ta,
    int* __restrict__ c_pt, int* __restrict__ c_tp, int* __restrict__ c_at,
    int* __restrict__ c_ta) {
  constexpr int B0 = kEPT, B1 = B0 + kETP, B2 = B1 + kEAT, B3 = B2 + kETA;
  int g = blockIdx.x * 256 + threadIdx.x;
  if (g < B0) atomicAdd(&c_pt[e_pt[kEPT + g]], 1);
  else if (g < B1) atomicAdd(&c_tp[e_tp[kETP + (g - B0)]], 1);
  else if (g < B2) atomicAdd(&c_at[e_at[kEAT + (g - B1)]], 1);
  else if (g < B3) atomicAdd(&c_ta[e_ta[kETA + (g - B2)]], 1);
}

__global__ __launch_bounds__(256) void scan1_b(const int* __restrict__ c0,
                                               const int* __restrict__ c1,
                                               const int* __restrict__ c2,
                                               const int* __restrict__ c3,
                                               int* __restrict__ part) {
  __shared__ int s[256];
  int ty = blockIdx.y;
  const int* cnt = (ty == 0) ? c0 : (ty == 1) ? c1 : (ty == 2) ? c2 : c3;
  int N = (ty == 0) ? kNT : (ty == 1) ? kNP : (ty == 2) ? kNT : kNA;
  int g = blockIdx.x * 256 + threadIdx.x;
  int t = threadIdx.x;
  s[t] = (g < N) ? cnt[g] : 0;
  __syncthreads();
  for (int o = 128; o > 0; o >>= 1) {
    if (t < o) s[t] += s[t + o];
    __syncthreads();
  }
  if (t == 0) part[ty * 1024 + blockIdx.x] = s[0];
}

__global__ __launch_bounds__(1024) void scan2_b(int* __restrict__ part) {
  __shared__ int s[1024];
  int ty = blockIdx.x;
  int nb = (ty == 0) ? ccdiv(kNT, 256)
           : (ty == 1) ? ccdiv(kNP, 256)
           : (ty == 2) ? ccdiv(kNT, 256)
                       : ccdiv(kNA, 256);
  int* p = part + ty * 1024;
  int t = threadIdx.x;
  int v = (t < nb) ? p[t] : 0;
  s[t] = v;
  __syncthreads();
  for (int o = 1; o < 1024; o <<= 1) {
    int x = (t >= o) ? s[t - o] : 0;
    __syncthreads();
    s[t] += x;
    __syncthreads();
  }
  if (t < nb) p[t] = s[t] - v;  // exclusive
}

__global__ __launch_bounds__(256) void scan3_b(
    const int* __restrict__ c0, const int* __restrict__ c1,
    const int* __restrict__ c2, const int* __restrict__ c3,
    const int* __restrict__ part, int* __restrict__ rp0, int* __restrict__ rp1,
    int* __restrict__ rp2, int* __restrict__ rp3) {
  __shared__ int s[256];
  int ty = blockIdx.y;
  const int* cnt = (ty == 0) ? c0 : (ty == 1) ? c1 : (ty == 2) ? c2 : c3;
  int* rp = (ty == 0) ? rp0 : (ty == 1) ? rp1 : (ty == 2) ? rp2 : rp3;
  int* cursor = (int*)cnt;  // cnt doubles as cursor
  int N = (ty == 0) ? kNT : (ty == 1) ? kNP : (ty == 2) ? kNT : kNA;
  int E = (ty == 0) ? kEPT : (ty == 1) ? kETP : (ty == 2) ? kEAT : kETA;
  int g = blockIdx.x * 256 + threadIdx.x;
  int t = threadIdx.x;
  int v = (g < N) ? cnt[g] : 0;
  s[t] = v;
  __syncthreads();
  for (int o = 1; o < 256; o <<= 1) {
    int x = (t >= o) ? s[t - o] : 0;
    __syncthreads();
    s[t] += x;
    __syncthreads();
  }
  if (g < N) {
    int excl = s[t] - v + part[ty * 1024 + blockIdx.x];
    rp[g] = excl;
    cursor[g] = excl;
    if (g == N - 1) rp[N] = E;
  }
}

__global__ __launch_bounds__(256) void fill_all(
    const int* __restrict__ e_pt, const int* __restrict__ e_tp,
    const int* __restrict__ e_at, const int* __restrict__ e_ta,
    int* __restrict__ cu0, int* __restrict__ cu1, int* __restrict__ cu2,
    int* __restrict__ cu3, int* __restrict__ co0, int* __restrict__ co1,
    int* __restrict__ co2, int* __restrict__ co3) {
  constexpr int B0 = kEPT, B1 = B0 + kETP, B2 = B1 + kEAT, B3 = B2 + kETA;
  int g = blockIdx.x * 256 + threadIdx.x;
  const int* e;
  int* cur;
  int* col;
  int E, l;
  if (g < B0) { e = e_pt; cur = cu0; col = co0; E = kEPT; l = g; }
  else if (g < B1) { e = e_tp; cur = cu1; col = co1; E = kETP; l = g - B0; }
  else if (g < B2) { e = e_at; cur = cu2; col = co2; E = kEAT; l = g - B1; }
  else if (g < B3) { e = e_ta; cur = cu3; col = co3; E = kETA; l = g - B2; }
  else return;
  int src = e[l];
  int dst = e[E + l];
  int p = atomicAdd(&cur[dst], 1);
  col[p] = src;
}

// ---------------- gathers (4-edge batched loads, fp32 acc, bf16 out) ---------

__device__ __forceinline__ void gacc(const short8* __restrict__ Xv, int ldx8,
                                     int off8c, const int* __restrict__ col,
                                     int s, int e, float acc[8]) {
  int j = s;
  for (; j + 4 <= e; j += 4) {
    short8 v0 = Xv[(size_t)col[j] * ldx8 + off8c];
    short8 v1 = Xv[(size_t)col[j + 1] * ldx8 + off8c];
    short8 v2 = Xv[(size_t)col[j + 2] * ldx8 + off8c];
    short8 v3 = Xv[(size_t)col[j + 3] * ldx8 + off8c];
#pragma unroll
    for (int i = 0; i < 8; ++i)
      acc[i] += (bf2f(v0[i]) + bf2f(v1[i])) + (bf2f(v2[i]) + bf2f(v3[i]));
  }
  for (; j < e; ++j) {
    short8 v = Xv[(size_t)col[j] * ldx8 + off8c];
#pragma unroll
    for (int i = 0; i < 8; ++i) acc[i] += bf2f(v[i]);
  }
}

// all four conv1 mean-gathers in one launch (128-d, 16 lanes/row)
__global__ __launch_bounds__(256) void gather4(
    const short* __restrict__ xpeb, const short* __restrict__ xaeb,
    const short* __restrict__ xtb, const int* __restrict__ rp_pt,
    const int* __restrict__ col_pt, short* __restrict__ aggpt,
    const int* __restrict__ rp_at, const int* __restrict__ col_at,
    short* __restrict__ aggat, const int* __restrict__ rp_tp,
    const int* __restrict__ col_tp, short* __restrict__ aggtp,
    const int* __restrict__ rp_ta, const int* __restrict__ col_ta,
    short* __restrict__ aggta) {
  constexpr int R0 = kNT, R1 = 2 * kNT, R2 = 2 * kNT + kNP,
                R3 = 2 * kNT + kNP + kNA;
  int g = blockIdx.x * 16 + (int)threadIdx.x / 16;
  int c = (int)threadIdx.x % 16;
  const short* X;
  const int* rp;
  const int* col;
  short* out;
  int r;
  if (g < R0) { X = xpeb; rp = rp_pt; col = col_pt; out = aggpt; r = g; }
  else if (g < R1) { X = xaeb; rp = rp_at; col = col_at; out = aggat; r = g - R0; }
  else if (g < R2) { X = xtb; rp = rp_tp; col = col_tp; out = aggtp; r = g - R1; }
  else if (g < R3) { X = xtb; rp = rp_ta; col = col_ta; out = aggta; r = g - R2; }
  else return;
  int s = rp[r], e = rp[r + 1];
  float acc[8] = {0.f, 0.f, 0.f, 0.f, 0.f, 0.f, 0.f, 0.f};
  gacc(reinterpret_cast<const short8*>(X), 16, c, col, s, e, acc);
  float inv = 1.0f / fmaxf((float)(e - s), 1.0f);
  short8 w;
#pragma unroll
  for (int i = 0; i < 8; ++i) w[i] = f2bf(acc[i] * inv);
  reinterpret_cast<short8*>(out)[(size_t)r * 16 + c] = w;
}

// conv2 tp/ta gathers from ypab (256-wide rows; tp reads cols 0-127, ta 128-255)
__global__ __launch_bounds__(256) void gather_tpta(
    const short* __restrict__ ypab, const int* __restrict__ rp_tp,
    const int* __restrict__ col_tp, short* __restrict__ g_tp,
    const int* __restrict__ rp_ta, const int* __restrict__ col_ta,
    short* __restrict__ g_ta) {
  int g = blockIdx.x * 16 + (int)threadIdx.x / 16;
  int c = (int)threadIdx.x % 16;
  const int* rp;
  const int* col;
  short* out;
  int r, off8;
  if (g < kNP) { rp = rp_tp; col = col_tp; out = g_tp; r = g; off8 = 0; }
  else if (g < kNP + kNA) { rp = rp_ta; col = col_ta; out = g_ta; r = g - kNP; off8 = 16; }
  else return;
  int s = rp[r], e = rp[r + 1];
  float acc[8] = {0.f, 0.f, 0.f, 0.f, 0.f, 0.f, 0.f, 0.f};
  gacc(reinterpret_cast<const short8*>(ypab), 32, off8 + c, col, s, e, acc);
  float inv = 1.0f / fmaxf((float)(e - s), 1.0f);
  short8 w;
#pragma unroll
  for (int i = 0; i < 8; ++i) w[i] = f2bf(acc[i] * inv);
  reinterpret_cast<short8*>(out)[(size_t)r * 16 + c] = w;
}

// out[g] = bf16( mean_pt(X1) + mean_at(X2) ), 128-d
__global__ __launch_bounds__(256) void gather2_b(
    const short* __restrict__ X1, const int* __restrict__ rp1,
    const int* __restrict__ col1, const short* __restrict__ X2,
    const int* __restrict__ rp2, const int* __restrict__ col2,
    short* __restrict__ out, int N) {
  int g = blockIdx.x * 16 + (int)threadIdx.x / 16;
  int c = (int)threadIdx.x % 16;
  if (g >= N) return;
  float tot[8] = {0.f, 0.f, 0.f, 0.f, 0.f, 0.f, 0.f, 0.f};
  {
    int s = rp1[g], e = rp1[g + 1];
    float a[8] = {0.f, 0.f, 0.f, 0.f, 0.f, 0.f, 0.f, 0.f};
    gacc(reinterpret_cast<const short8*>(X1), 16, c, col1, s, e, a);
    float inv = 1.0f / fmaxf((float)(e - s), 1.0f);
#pragma unroll
    for (int i = 0; i < 8; ++i) tot[i] += a[i] * inv;
  }
  {
    int s = rp2[g], e = rp2[g + 1];
    float a[8] = {0.f, 0.f, 0.f, 0.f, 0.f, 0.f, 0.f, 0.f};
    gacc(reinterpret_cast<const short8*>(X2), 16, c, col2, s, e, a);
    float inv = 1.0f / fmaxf((float)(e - s), 1.0f);
#pragma unroll
    for (int i = 0; i < 8; ++i) tot[i] += a[i] * inv;
  }
  short8 w;
#pragma unroll
  for (int i = 0; i < 8; ++i) w[i] = f2bf(tot[i]);
  reinterpret_cast<short8*>(out)[(size_t)g * 16 + c] = w;
}

// ------- MFMA GEMM v5 (unchanged from R8): 8 waves, B-first, gll dbuf --------
template <int K, int DOUT, int NA, bool BF16OUT, bool BIAS, bool RELU,
          bool HASADD>
__global__ __launch_bounds__(512, 4) void mfma_gemm(
    const short* __restrict__ A0, const short* __restrict__ A1,
    const short* __restrict__ A2, const short* __restrict__ B0,
    const short* __restrict__ B1, const short* __restrict__ B2,
    const float* __restrict__ bias, const short* __restrict__ add0,
    float* __restrict__ Cf, short* __restrict__ Cb, int N) {
  constexpr int WC = (DOUT == 256) ? 8 : 4;
  constexpr int WR = 8 / WC;
  constexpr int TM = 4 / WR;
  constexpr int TN = DOUT / WC / 16;
  constexpr int CPK = K / 128;
  constexpr int NCHUNK = NA * CPK;
  constexpr int KCH = K / 32;

  __shared__ short As[2][64 * 128];

  const int tid = threadIdx.x;
  const int lane = tid & 63;
  const int w = tid >> 6;
  const int wc = w % WC;
  const int wr = w / WC;
  const int lr = lane & 15;
  const int ls = lane >> 4;
  const int n0 = blockIdx.x * 64;

  const short* Ap[3] = {A0, A1, A2};
  const short* Bp[3] = {B0, B1, B2};

  auto stage = [&](int buf, int a, int kc) {
#pragma unroll
    for (int it = 0; it < 2; ++it) {
      int u = it * 512 + w * 64 + lane;
      int row = u >> 4;
      int c8s = u & 15;
      int n = n0 + row;
      if (n >= N) n = N - 1;
      const short* g = Ap[a] + (size_t)n * K + kc + ((c8s ^ (row & 7)) << 3);
      short* l = &As[buf][(it * 512 + w * 64) * 8];
      __builtin_amdgcn_global_load_lds(
          (const __attribute__((address_space(1))) void*)g,
          (__attribute__((address_space(3))) void*)l, 16, 0, 0);
    }
  };

  f32x4 acc[TM][TN] = {};

  stage(0, 0, 0);
  __syncthreads();

#pragma unroll
  for (int c = 0; c < NCHUNK; ++c) {
    const int buf = c & 1;
    const int a = c / CPK;
    const int kc32 = (c % CPK) * 4;
    const short* Ba = Bp[a];

    short8 bfr[4][TN];
#pragma unroll
    for (int kk = 0; kk < 4; ++kk)
#pragma unroll
      for (int tn = 0; tn < TN; ++tn)
        bfr[kk][tn] = *reinterpret_cast<const short8*>(
            Ba + ((size_t)((wc * TN + tn) * KCH + kc32 + kk) * 64 + lane) * 8);
    __builtin_amdgcn_sched_barrier(0);
    if (c + 1 < NCHUNK)
      stage(buf ^ 1, (c + 1) / CPK, ((c + 1) % CPK) * 128);
    __builtin_amdgcn_sched_barrier(0);
#pragma unroll
    for (int kk = 0; kk < 4; ++kk) {
#pragma unroll
      for (int tm = 0; tm < TM; ++tm) {
        int row = wr * TM * 16 + tm * 16 + lr;
        short8 af = *reinterpret_cast<const short8*>(
            &As[buf][(row * 128 + (kk * 4 + ls) * 8) ^ ((row & 7) << 3)]);
#pragma unroll
        for (int tn = 0; tn < TN; ++tn)
          acc[tm][tn] = __builtin_amdgcn_mfma_f32_16x16x32_bf16(
              af, bfr[kk][tn], acc[tm][tn], 0, 0, 0);
      }
    }
    __syncthreads();
  }

#pragma unroll
  for (int tm = 0; tm < TM; ++tm) {
#pragma unroll
    for (int tn = 0; tn < TN; ++tn) {
      int colg = wc * TN * 16 + tn * 16 + lr;
      float bv = 0.f;
      if constexpr (BIAS) bv = bias[colg];
#pragma unroll
      for (int r = 0; r < 4; ++r) {
        int n = n0 + wr * TM * 16 + tm * 16 + ls * 4 + r;
        if (n < N) {
          float v = acc[tm][tn][r] + bv;
          if constexpr (HASADD) v += bf2f(add0[(size_t)n * DOUT + colg]);
          if constexpr (RELU) v = fmaxf(v, 0.f);
          if constexpr (BF16OUT)
            Cb[(size_t)n * DOUT + colg] = f2bf(v);
          else
            Cf[(size_t)n * DOUT + colg] = v;
        }
      }
    }
  }
}

}  // namespace

extern "C" void kernel_launch(void* const* d_in, const int* in_sizes, int n_in,
                              void* d_out, int out_size, void* d_ws,
                              size_t ws_size, hipStream_t stream) {
  const float* x_p   = (const float*)d_in[0];
  const float* x_t   = (const float*)d_in[1];
  const float* x_a   = (const float*)d_in[2];
  const float* emb_p = (const float*)d_in[3];
  const float* emb_a = (const float*)d_in[4];
  const float* W1l   = (const float*)d_in[5];
  const float* b1    = (const float*)d_in[6];
  const float* W1r   = (const float*)d_in[7];
  const float* W2l   = (const float*)d_in[8];
  const float* b2    = (const float*)d_in[9];
  const float* W2r   = (const float*)d_in[10];
  const float* Wres  = (const float*)d_in[11];
  const float* bres  = (const float*)d_in[12];
  const int* e_pt = (const int*)d_in[13];
  const int* e_tp = (const int*)d_in[14];
  const int* e_at = (const int*)d_in[15];
  const int* e_ta = (const int*)d_in[16];
  (void)in_sizes; (void)n_in; (void)out_size; (void)ws_size;

  float* out = (float*)d_out;
  float* p_out = out;
  float* t_out = out + (size_t)kNP * DO;
  float* a_out = out + (size_t)(kNP + kNT) * DO;

  char* base = (char*)d_ws;
  size_t off = 0;
  auto alloc = [&](size_t bytes) {
    off = (off + 255) & ~size_t(255);
    void* p = base + off;
    off += bytes;
    return p;
  };

  short* t1b   = (short*)alloc((size_t)kNT * DH * 2);
  short* p1b   = (short*)alloc((size_t)kNP * DH * 2);
  short* a1b   = (short*)alloc((size_t)kNA * DH * 2);
  short* aggpt = (short*)alloc((size_t)kNT * DIN * 2);  // later: gt, then ypab
  short* aggat = (short*)alloc((size_t)kNT * DIN * 2);  // (ypab spans these)
  short* aggtp = (short*)alloc((size_t)kNP * DIN * 2);
  short* aggta = (short*)alloc((size_t)kNA * DIN * 2);
  short* xpeb  = (short*)alloc((size_t)kNP * DIN * 2);
  short* xaeb  = (short*)alloc((size_t)kNA * DIN * 2);
  short* xtb   = (short*)alloc((size_t)kNT * DIN * 2);
  short* ypb   = (short*)alloc((size_t)kNP * DO * 2);
  short* yab   = (short*)alloc((size_t)kNA * DO * 2);
  short* g_tp  = (short*)alloc((size_t)kNP * DO * 2);
  short* g_ta  = (short*)alloc((size_t)kNA * DO * 2);
  short* w1l_rm  = (short*)alloc(4 * per1 * 2);
  short* w1r_rm  = (short*)alloc(4 * per1 * 2);
  short* w1rc_rm = (short*)alloc(per1 * 2);
  short* w2l_rm  = (short*)alloc(4 * per2 * 2);
  short* wc_rm   = (short*)alloc(3 * per2 * 2);
  short* w1lb   = (short*)alloc(4 * per1 * 2);
  short* w1rb   = (short*)alloc(4 * per1 * 2);
  short* w1rcb  = (short*)alloc(per1 * 2);
  short* w2lb   = (short*)alloc(4 * per2 * 2);
  short* wcb    = (short*)alloc(3 * per2 * 2);
  short* w2lpab = (short*)alloc(2 * per2 * 2);
  float* bc     = (float*)alloc(3 * DO * 4);
  float* b1ct   = (float*)alloc(DH * 4);

  int* rp_pt  = (int*)alloc((kNT + 1) * 4);
  int* rp_tp  = (int*)alloc((kNP + 1) * 4);
  int* rp_at  = (int*)alloc((kNT + 1) * 4);
  int* rp_ta  = (int*)alloc((kNA + 1) * 4);
  int* cur_pt = (int*)alloc(kNT * 4);
  int* cur_tp = (int*)alloc(kNP * 4);
  int* cur_at = (int*)alloc(kNT * 4);
  int* cur_ta = (int*)alloc(kNA * 4);
  int* col_pt = (int*)alloc(kEPT * 4);
  int* col_tp = (int*)alloc(kETP * 4);
  int* col_at = (int*)alloc(kEAT * 4);
  int* col_ta = (int*)alloc(kETA * 4);
  int* part   = (int*)alloc(4 * 1024 * 4);

  // ---- 0. fused converts ----
  {
    int tot = kNP * DIN / 8 + kNA * DIN / 8 + kNT * DIN / 8;
    cvt_all<<<cdiv(tot, 256), 256, 0, stream>>>(x_p, emb_p, xpeb, x_a, emb_a,
                                                xaeb, x_t, xtb);
  }

  // ---- 1. fused weight prep + fragment swizzle ----
  {
    int tot = 4 * per1 + 4 * per1 + per1 + 4 * per2 + 3 * per2 + DH;
    prep_all<<<cdiv(tot, 256), 256, 0, stream>>>(
        W1l, W1r, W2l, Wres, W2r, bres, b2, b1, w1l_rm, w1r_rm, w1rc_rm,
        w2l_rm, wc_rm, bc, b1ct);
    swizzle_all<<<cdiv(73728, 256), 256, 0, stream>>>(
        w1l_rm, w1lb, w1r_rm, w1rb, w1rc_rm, w1rcb, w2l_rm, w2lb, wc_rm, wcb,
        w2lpab);
  }

  // ---- 2. CSR build (batched) ----
  {
    size_t span = (size_t)((char*)cur_ta + kNA * 4 - (char*)cur_pt);
    hipMemsetAsync(cur_pt, 0, span, stream);
    int totE = kEPT + kETP + kEAT + kETA;
    hist_all<<<cdiv(totE, 256), 256, 0, stream>>>(e_pt, e_tp, e_at, e_ta,
                                                  cur_pt, cur_tp, cur_at,
                                                  cur_ta);
    dim3 sg(cdiv(kNT, 256), 4);
    scan1_b<<<sg, 256, 0, stream>>>(cur_pt, cur_tp, cur_at, cur_ta, part);
    scan2_b<<<4, 1024, 0, stream>>>(part);
    scan3_b<<<sg, 256, 0, stream>>>(cur_pt, cur_tp, cur_at, cur_ta, part,
                                    rp_pt, rp_tp, rp_at, rp_ta);
    fill_all<<<cdiv(totE, 256), 256, 0, stream>>>(
        e_pt, e_tp, e_at, e_ta, cur_pt, cur_tp, cur_at, cur_ta, col_pt, col_tp,
        col_at, col_ta);
  }

  // ---- 3. conv1 gathers (one launch) ----
  gather4<<<cdiv(2 * kNT + kNP + kNA, 16), 256, 0, stream>>>(
      xpeb, xaeb, xtb, rp_pt, col_pt, aggpt, rp_at, col_at, aggat, rp_tp,
      col_tp, aggtp, rp_ta, col_ta, aggta);

  // ---- 4. conv1 GEMMs ----
  mfma_gemm<DIN, DH, 3, true, true, true, false>
      <<<cdiv(kNT, 64), 512, 0, stream>>>(aggpt, aggat, xtb, w1lb,
                                          w1lb + 2 * per1, w1rcb, b1ct, nullptr,
                                          nullptr, t1b, kNT);
  mfma_gemm<DIN, DH, 2, true, true, true, false>
      <<<cdiv(kNP, 64), 512, 0, stream>>>(aggtp, xpeb, nullptr, w1lb + 1 * per1,
                                          w1rb + 1 * per1, nullptr, b1 + 1 * DH,
                                          nullptr, nullptr, p1b, kNP);
  mfma_gemm<DIN, DH, 2, true, true, true, false>
      <<<cdiv(kNA, 64), 512, 0, stream>>>(aggta, xaeb, nullptr, w1lb + 3 * per1,
                                          w1rb + 3 * per1, nullptr, b1 + 3 * DH,
                                          nullptr, nullptr, a1b, kNA);

  // ---- 5. conv2 down-projections for the track terms ----
  mfma_gemm<DH, DO, 1, true, false, false, false>
      <<<cdiv(kNP, 64), 512, 0, stream>>>(p1b, nullptr, nullptr, w2lb, nullptr,
                                          nullptr, nullptr, nullptr, nullptr,
                                          ypb, kNP);
  mfma_gemm<DH, DO, 1, true, false, false, false>
      <<<cdiv(kNA, 64), 512, 0, stream>>>(a1b, nullptr, nullptr,
                                          w2lb + 2 * per2, nullptr, nullptr,
                                          nullptr, nullptr, nullptr, yab, kNA);

  // ---- 6. gt = mean_pt(y_p) + mean_at(y_a), fused t_out GEMM ----
  short* gt = aggpt;  // free after conv1-t GEMM
  gather2_b<<<cdiv(kNT, 16), 256, 0, stream>>>(ypb, rp_pt, col_pt, yab, rp_at,
                                               col_at, gt, kNT);
  mfma_gemm<DH, DO, 1, false, true, false, true>
      <<<cdiv(kNT, 64), 512, 0, stream>>>(t1b, nullptr, nullptr, wcb, nullptr,
                                          nullptr, bc, gt, t_out, nullptr,
                                          kNT);

  // ---- 7. y_pa = t1 @ [W2l1;W2l3]^T ----
  short* ypab = aggpt;  // spans aggpt..aggat region
  mfma_gemm<DH, 256, 1, true, false, false, false>
      <<<cdiv(kNT, 64), 512, 0, stream>>>(t1b, nullptr, nullptr, w2lpab,
                                          nullptr, nullptr, nullptr, nullptr,
                                          nullptr, ypab, kNT);

  // ---- 8. conv2 tp/ta gathers (one launch) ----
  gather_tpta<<<cdiv(kNP + kNA, 16), 256, 0, stream>>>(
      ypab, rp_tp, col_tp, g_tp, rp_ta, col_ta, g_ta);

  // ---- 9. p_out / a_out ----
  mfma_gemm<DH, DO, 1, false, true, false, true>
      <<<cdiv(kNP, 64), 512, 0, stream>>>(p1b, nullptr, nullptr, wcb + per2,
                                          nullptr, nullptr, bc + DO, g_tp,
                                          p_out, nullptr, kNP);
  mfma_gemm<DH, DO, 1, false, true, false, true>
      <<<cdiv(kNA, 64), 512, 0, stream>>>(a1b, nullptr, nullptr,
                                          wcb + 2 * per2, nullptr, nullptr,
                                          bc + 2 * DO, g_ta, a_out, nullptr,
                                          kNA);
}

// Round 10
// 702.607 us; speedup vs baseline: 1.6786x; 1.2882x over previous
//
#include <hip/hip_runtime.h>

namespace {

typedef __attribute__((ext_vector_type(8))) short short8;
typedef __attribute__((ext_vector_type(4))) float f32x4;

constexpr int kNP = 50000, kNT = 200000, kNA = 20000;
constexpr int kEPT = 1000000, kETP = 1000000, kEAT = 400000, kETA = 400000;
constexpr int DIN = 128, DH = 256, DO = 128;
constexpr int per1 = DIN * DH;  // 32768
constexpr int per2 = DH * DO;   // 32768

__device__ __forceinline__ float bf2f(short u) {
  union { unsigned int i; float f; } c;
  c.i = ((unsigned int)(unsigned short)u) << 16;
  return c.f;
}
__device__ __forceinline__ short f2bf(float f) {
  union { float f; unsigned int i; } c;
  c.f = f;
  unsigned int r = c.i + 0x7fffu + ((c.i >> 16) & 1u);  // RNE
  return (short)(r >> 16);
}

inline int cdiv(int a, int b) { return (a + b - 1) / b; }
constexpr int ccdiv(int a, int b) { return (a + b - 1) / b; }

// ---------------- fused convert: xpe, xae, xt -> bf16 ----------------

__global__ __launch_bounds__(256) void cvt_all(
    const float* __restrict__ x_p, const float* __restrict__ emb_p,
    short* __restrict__ xpeb, const float* __restrict__ x_a,
    const float* __restrict__ emb_a, short* __restrict__ xaeb,
    const float* __restrict__ x_t, short* __restrict__ xtb) {
  constexpr int N0 = kNP * DIN / 8;
  constexpr int N1 = N0 + kNA * DIN / 8;
  constexpr int N2 = N1 + kNT * DIN / 8;
  int g = blockIdx.x * 256 + threadIdx.x;
  const float* a;
  const float* b = nullptr;
  short* o;
  int i;
  if (g < N0) { a = x_p; b = emb_p; o = xpeb; i = g; }
  else if (g < N1) { a = x_a; b = emb_a; o = xaeb; i = g - N0; }
  else if (g < N2) { a = x_t; o = xtb; i = g - N1; }
  else return;
  const float4* a4 = reinterpret_cast<const float4*>(a);
  float4 x0 = a4[2 * i], x1 = a4[2 * i + 1];
  if (b != nullptr) {
    const float4* b4 = reinterpret_cast<const float4*>(b);
    float4 y0 = b4[2 * i], y1 = b4[2 * i + 1];
    x0.x += y0.x; x0.y += y0.y; x0.z += y0.z; x0.w += y0.w;
    x1.x += y1.x; x1.y += y1.y; x1.z += y1.z; x1.w += y1.w;
  }
  short8 w;
  w[0] = f2bf(x0.x); w[1] = f2bf(x0.y); w[2] = f2bf(x0.z); w[3] = f2bf(x0.w);
  w[4] = f2bf(x1.x); w[5] = f2bf(x1.y); w[6] = f2bf(x1.z); w[7] = f2bf(x1.w);
  reinterpret_cast<short8*>(o)[i] = w;
}

// ---------------- fused weight prep (row-major bf16 + fp32 biases) -----------

__global__ __launch_bounds__(256) void prep_all(
    const float* __restrict__ W1l, const float* __restrict__ W1r,
    const float* __restrict__ W2l, const float* __restrict__ Wres,
    const float* __restrict__ W2r, const float* __restrict__ bres,
    const float* __restrict__ b2, const float* __restrict__ b1,
    short* __restrict__ w1l_rm, short* __restrict__ w1r_rm,
    short* __restrict__ w1rc_rm, short* __restrict__ w2l_rm,
    short* __restrict__ wc_rm, float* __restrict__ bc,
    float* __restrict__ b1ct) {
  constexpr int P0 = 4 * per1;
  constexpr int P1 = P0 + 4 * per1;
  constexpr int P2 = P1 + per1;
  constexpr int P3 = P2 + 4 * per2;
  constexpr int P4 = P3 + 3 * per2;
  constexpr int P5 = P4 + DH;
  int g = blockIdx.x * 256 + threadIdx.x;
  if (g < P0) {
    int e = g / per1;
    float s = (e == 0 || e == 2) ? 0.5f : 1.0f;
    w1l_rm[g] = f2bf(W1l[g] * s);
  } else if (g < P1) {
    int l = g - P0;
    w1r_rm[l] = f2bf(W1r[l]);
  } else if (g < P2) {
    int l = g - P1;
    w1rc_rm[l] = f2bf(0.5f * (W1r[l] + W1r[2 * per1 + l]));
  } else if (g < P3) {
    int l = g - P2;
    int e = l / per2;
    float s = (e == 0 || e == 2) ? 0.5f : 1.0f;
    w2l_rm[l] = f2bf(W2l[l] * s);
  } else if (g < P4) {
    int l = g - P3;
    {
      int b = l / per2;
      int idx = l - b * per2;
      int resIdx = (b == 0) ? 1 : (b == 1) ? 0 : 2;
      float v = Wres[(size_t)resIdx * per2 + idx];
      if (b == 0)
        v += 0.5f * (W2r[idx] + W2r[(size_t)2 * per2 + idx]);
      else if (b == 1)
        v += W2r[(size_t)1 * per2 + idx];
      else
        v += W2r[(size_t)3 * per2 + idx];
      wc_rm[l] = f2bf(v);
    }
    if (l < 3 * DO) {
      int b = l / DO;
      int o = l - b * DO;
      int resIdx = (b == 0) ? 1 : (b == 1) ? 0 : 2;
      float v = bres[resIdx * DO + o];
      if (b == 0)
        v += 0.5f * (b2[0 * DO + o] + b2[2 * DO + o]);
      else if (b == 1)
        v += b2[1 * DO + o];
      else
        v += b2[3 * DO + o];
      bc[l] = v;
    }
  } else if (g < P5) {
    int l = g - P4;
    b1ct[l] = 0.5f * (b1[l] + b1[2 * DH + l]);
  }
}

// ---------------- fragment swizzle (all weights, one launch) ------------------

__device__ __forceinline__ void swz1(const short* __restrict__ in,
                                     short* __restrict__ out, int t, int D,
                                     int Kk) {
  int kch = Kk / 32;
  int per8 = D * Kk / 8;
  int m = t / per8;
  int tt = t - m * per8;
  int cg = tt / (kch * 64);
  int r1 = tt - cg * kch * 64;
  int kc = r1 >> 6;
  int lane = r1 & 63;
  int ls = lane >> 4, lr = lane & 15;
  const short* src = in + (size_t)m * D * Kk + (size_t)(cg * 16 + lr) * Kk +
                     kc * 32 + ls * 8;
  short8 v = *reinterpret_cast<const short8*>(src);
  reinterpret_cast<short8*>(out + (size_t)m * D * Kk)[tt] = v;
}

__global__ __launch_bounds__(256) void swizzle_all(
    const short* __restrict__ w1l_rm, short* __restrict__ w1lb,
    const short* __restrict__ w1r_rm, short* __restrict__ w1rb,
    const short* __restrict__ w1rc_rm, short* __restrict__ w1rcb,
    const short* __restrict__ w2l_rm, short* __restrict__ w2lb,
    const short* __restrict__ wc_rm, short* __restrict__ wcb,
    short* __restrict__ w2lpab) {
  constexpr int S0 = 4 * per1 / 8;
  constexpr int S1 = S0 + 4 * per1 / 8;
  constexpr int S2 = S1 + per1 / 8;
  constexpr int S3 = S2 + 4 * per2 / 8;
  constexpr int S4 = S3 + 3 * per2 / 8;
  constexpr int S5 = S4 + per2 / 8;
  constexpr int S6 = S5 + per2 / 8;
  int g = blockIdx.x * 256 + threadIdx.x;
  if (g < S0) swz1(w1l_rm, w1lb, g, DH, DIN);
  else if (g < S1) swz1(w1r_rm, w1rb, g - S0, DH, DIN);
  else if (g < S2) swz1(w1rc_rm, w1rcb, g - S1, DH, DIN);
  else if (g < S3) swz1(w2l_rm, w2lb, g - S2, DO, DH);
  else if (g < S4) swz1(wc_rm, wcb, g - S3, DO, DH);
  else if (g < S5) swz1(w2l_rm + per2, w2lpab, g - S4, DO, DH);
  else if (g < S6) swz1(w2l_rm + 3 * per2, w2lpab + per2, g - S5, DO, DH);
}

// ---------------- CSR build v2: bucketed counting sort ----------------
// Buckets of 256 dst nodes. bh/gcur: per-type nb entries; bb: nb+1 entries.

constexpr int NB0 = ccdiv(kNT, 256);  // 782 (pt)
constexpr int NB1 = ccdiv(kNP, 256);  // 196 (tp)
constexpr int NB2 = ccdiv(kNT, 256);  // 782 (at)
constexpr int NB3 = ccdiv(kNA, 256);  // 79  (ta)
constexpr int NBTOT = NB0 + NB1 + NB2 + NB3;          // 1839
constexpr int BBTOT = NBTOT + 4;
constexpr int CHUNK = 16384;
constexpr int C0 = ccdiv(kEPT, CHUNK), C1 = ccdiv(kETP, CHUNK),
              C2 = ccdiv(kEAT, CHUNK), C3 = ccdiv(kETA, CHUNK);
constexpr int CBTOT = C0 + C1 + C2 + C3;

struct TyInfo {
  const int* ep; int E; int nb; int bhoff; int boff; int eoff; int cb;
};

__device__ __forceinline__ TyInfo ty_from_block(
    int blk, const int* e0, const int* e1, const int* e2, const int* e3) {
  TyInfo ti;
  if (blk < C0) { ti = {e0, kEPT, NB0, 0, 0, 0, blk}; }
  else if (blk < C0 + C1) {
    ti = {e1, kETP, NB1, NB0, NB0 + 1, kEPT, blk - C0};
  } else if (blk < C0 + C1 + C2) {
    ti = {e2, kEAT, NB2, NB0 + NB1, NB0 + NB1 + 2, kEPT + kETP, blk - C0 - C1};
  } else {
    ti = {e3, kETA, NB3, NB0 + NB1 + NB2, NB0 + NB1 + NB2 + 3,
          kEPT + kETP + kEAT, blk - C0 - C1 - C2};
  }
  return ti;
}

__global__ __launch_bounds__(256) void bucket_hist(
    const int* __restrict__ e0, const int* __restrict__ e1,
    const int* __restrict__ e2, const int* __restrict__ e3,
    int* __restrict__ bh) {
  __shared__ int h[NB0];
  TyInfo ti = ty_from_block(blockIdx.x, e0, e1, e2, e3);
  const int* dstp = ti.ep + ti.E;
  for (int i = threadIdx.x; i < ti.nb; i += 256) h[i] = 0;
  __syncthreads();
  int jend = min(ti.E, (ti.cb + 1) * CHUNK);
  for (int j = ti.cb * CHUNK + threadIdx.x; j < jend; j += 256)
    atomicAdd(&h[dstp[j] >> 8], 1);
  __syncthreads();
  for (int i = threadIdx.x; i < ti.nb; i += 256) {
    int v = h[i];
    if (v) atomicAdd(&bh[ti.bhoff + i], v);
  }
}

__global__ __launch_bounds__(1024) void bucket_scan(const int* __restrict__ bh,
                                                    int* __restrict__ bb,
                                                    int* __restrict__ gcur) {
  __shared__ int s[1024];
  int ty = blockIdx.x;
  int nb = (ty == 0) ? NB0 : (ty == 1) ? NB1 : (ty == 2) ? NB2 : NB3;
  int E = (ty == 0) ? kEPT : (ty == 1) ? kETP : (ty == 2) ? kEAT : kETA;
  int bhoff = (ty == 0) ? 0 : (ty == 1) ? NB0 : (ty == 2) ? NB0 + NB1
                                               : NB0 + NB1 + NB2;
  int boff = bhoff + ty;  // bb has +1 per preceding type
  int t = threadIdx.x;
  int v = (t < nb) ? bh[bhoff + t] : 0;
  s[t] = v;
  __syncthreads();
  for (int o = 1; o < 1024; o <<= 1) {
    int x = (t >= o) ? s[t - o] : 0;
    __syncthreads();
    s[t] += x;
    __syncthreads();
  }
  if (t < nb) {
    int ex = s[t] - v;
    bb[boff + t] = ex;
    gcur[bhoff + t] = ex;
  }
  if (t == 0) bb[boff + nb] = E;
}

__global__ __launch_bounds__(256) void bin_edges(
    const int* __restrict__ e0, const int* __restrict__ e1,
    const int* __restrict__ e2, const int* __restrict__ e3,
    int* __restrict__ gcur, int* __restrict__ bin) {
  __shared__ int h[NB0];
  __shared__ int hb[NB0];
  TyInfo ti = ty_from_block(blockIdx.x, e0, e1, e2, e3);
  const int* dstp = ti.ep + ti.E;
  for (int i = threadIdx.x; i < ti.nb; i += 256) h[i] = 0;
  __syncthreads();
  int j0 = ti.cb * CHUNK + threadIdx.x;
  int jend = min(ti.E, (ti.cb + 1) * CHUNK);
  for (int j = j0; j < jend; j += 256) atomicAdd(&h[dstp[j] >> 8], 1);
  __syncthreads();
  for (int i = threadIdx.x; i < ti.nb; i += 256) {
    int v = h[i];
    hb[i] = v ? atomicAdd(&gcur[ti.bhoff + i], v) : 0;
    h[i] = 0;
  }
  __syncthreads();
  for (int j = j0; j < jend; j += 256) {
    int d = dstp[j];
    int b = d >> 8;
    int pos = hb[b] + atomicAdd(&h[b], 1);
    bin[ti.eoff + pos] = ti.ep[j] | ((d & 255) << 24);
  }
}

__global__ __launch_bounds__(256) void fine_fill(
    const int* __restrict__ bin, const int* __restrict__ bb,
    int* __restrict__ rp0, int* __restrict__ rp1, int* __restrict__ rp2,
    int* __restrict__ rp3, int* __restrict__ co0, int* __restrict__ co1,
    int* __restrict__ co2, int* __restrict__ co3) {
  __shared__ int cnt[256];
  __shared__ int excl[256];
  int b = blockIdx.x;
  int ty, lb;
  if (b < NB0) { ty = 0; lb = b; }
  else if (b < NB0 + NB1) { ty = 1; lb = b - NB0; }
  else if (b < NB0 + NB1 + NB2) { ty = 2; lb = b - NB0 - NB1; }
  else { ty = 3; lb = b - NB0 - NB1 - NB2; }
  int nb = (ty == 0) ? NB0 : (ty == 1) ? NB1 : (ty == 2) ? NB2 : NB3;
  int N = (ty == 0) ? kNT : (ty == 1) ? kNP : (ty == 2) ? kNT : kNA;
  int E = (ty == 0) ? kEPT : (ty == 1) ? kETP : (ty == 2) ? kEAT : kETA;
  int bhoff = (ty == 0) ? 0 : (ty == 1) ? NB0 : (ty == 2) ? NB0 + NB1
                                               : NB0 + NB1 + NB2;
  int boff = bhoff + ty;
  int eoff = (ty == 0) ? 0 : (ty == 1) ? kEPT : (ty == 2) ? kEPT + kETP
                                                : kEPT + kETP + kEAT;
  int* rp = (ty == 0) ? rp0 : (ty == 1) ? rp1 : (ty == 2) ? rp2 : rp3;
  int* col = (ty == 0) ? co0 : (ty == 1) ? co1 : (ty == 2) ? co2 : co3;

  int base = bb[boff + lb];
  int end = bb[boff + lb + 1];
  int t = threadIdx.x;
  cnt[t] = 0;
  __syncthreads();
  for (int j = base + t; j < end; j += 256)
    atomicAdd(&cnt[(bin[eoff + j] >> 24) & 255], 1);
  __syncthreads();
  int v = cnt[t];
  excl[t] = v;
  __syncthreads();
  for (int o = 1; o < 256; o <<= 1) {
    int x = (t >= o) ? excl[t - o] : 0;
    __syncthreads();
    excl[t] += x;
    __syncthreads();
  }
  excl[t] -= v;  // exclusive
  cnt[t] = 0;    // reuse as cursor
  __syncthreads();
  int node = (lb << 8) + t;
  if (node < N) rp[node] = base + excl[t];
  if (lb == nb - 1 && t == 0) rp[N] = E;
  for (int j = base + t; j < end; j += 256) {
    int v2 = bin[eoff + j];
    int l = (v2 >> 24) & 255;
    int pos = base + excl[l] + atomicAdd(&cnt[l], 1);
    col[pos] = v2 & 0xFFFFFF;
  }
}

// ---------------- gathers (4-edge batched loads, fp32 acc, bf16 out) ---------

__device__ __forceinline__ void gacc(const short8* __restrict__ Xv, int ldx8,
                                     int off8c, const int* __restrict__ col,
                                     int s, int e, float acc[8]) {
  int j = s;
  for (; j + 4 <= e; j += 4) {
    short8 v0 = Xv[(size_t)col[j] * ldx8 + off8c];
    short8 v1 = Xv[(size_t)col[j + 1] * ldx8 + off8c];
    short8 v2 = Xv[(size_t)col[j + 2] * ldx8 + off8c];
    short8 v3 = Xv[(size_t)col[j + 3] * ldx8 + off8c];
#pragma unroll
    for (int i = 0; i < 8; ++i)
      acc[i] += (bf2f(v0[i]) + bf2f(v1[i])) + (bf2f(v2[i]) + bf2f(v3[i]));
  }
  for (; j < e; ++j) {
    short8 v = Xv[(size_t)col[j] * ldx8 + off8c];
#pragma unroll
    for (int i = 0; i < 8; ++i) acc[i] += bf2f(v[i]);
  }
}

__global__ __launch_bounds__(256) void gather4(
    const short* __restrict__ xpeb, const short* __restrict__ xaeb,
    const short* __restrict__ xtb, const int* __restrict__ rp_pt,
    const int* __restrict__ col_pt, short* __restrict__ aggpt,
    const int* __restrict__ rp_at, const int* __restrict__ col_at,
    short* __restrict__ aggat, const int* __restrict__ rp_tp,
    const int* __restrict__ col_tp, short* __restrict__ aggtp,
    const int* __restrict__ rp_ta, const int* __restrict__ col_ta,
    short* __restrict__ aggta) {
  constexpr int R0 = kNT, R1 = 2 * kNT, R2 = 2 * kNT + kNP,
                R3 = 2 * kNT + kNP + kNA;
  int g = blockIdx.x * 16 + (int)threadIdx.x / 16;
  int c = (int)threadIdx.x % 16;
  const short* X;
  const int* rp;
  const int* col;
  short* out;
  int r;
  if (g < R0) { X = xpeb; rp = rp_pt; col = col_pt; out = aggpt; r = g; }
  else if (g < R1) { X = xaeb; rp = rp_at; col = col_at; out = aggat; r = g - R0; }
  else if (g < R2) { X = xtb; rp = rp_tp; col = col_tp; out = aggtp; r = g - R1; }
  else if (g < R3) { X = xtb; rp = rp_ta; col = col_ta; out = aggta; r = g - R2; }
  else return;
  int s = rp[r], e = rp[r + 1];
  float acc[8] = {0.f, 0.f, 0.f, 0.f, 0.f, 0.f, 0.f, 0.f};
  gacc(reinterpret_cast<const short8*>(X), 16, c, col, s, e, acc);
  float inv = 1.0f / fmaxf((float)(e - s), 1.0f);
  short8 w;
#pragma unroll
  for (int i = 0; i < 8; ++i) w[i] = f2bf(acc[i] * inv);
  reinterpret_cast<short8*>(out)[(size_t)r * 16 + c] = w;
}

__global__ __launch_bounds__(256) void gather_tpta(
    const short* __restrict__ ypab, const int* __restrict__ rp_tp,
    const int* __restrict__ col_tp, short* __restrict__ g_tp,
    const int* __restrict__ rp_ta, const int* __restrict__ col_ta,
    short* __restrict__ g_ta) {
  int g = blockIdx.x * 16 + (int)threadIdx.x / 16;
  int c = (int)threadIdx.x % 16;
  const int* rp;
  const int* col;
  short* out;
  int r, off8;
  if (g < kNP) { rp = rp_tp; col = col_tp; out = g_tp; r = g; off8 = 0; }
  else if (g < kNP + kNA) { rp = rp_ta; col = col_ta; out = g_ta; r = g - kNP; off8 = 16; }
  else return;
  int s = rp[r], e = rp[r + 1];
  float acc[8] = {0.f, 0.f, 0.f, 0.f, 0.f, 0.f, 0.f, 0.f};
  gacc(reinterpret_cast<const short8*>(ypab), 32, off8 + c, col, s, e, acc);
  float inv = 1.0f / fmaxf((float)(e - s), 1.0f);
  short8 w;
#pragma unroll
  for (int i = 0; i < 8; ++i) w[i] = f2bf(acc[i] * inv);
  reinterpret_cast<short8*>(out)[(size_t)r * 16 + c] = w;
}

__global__ __launch_bounds__(256) void gather2_b(
    const short* __restrict__ X1, const int* __restrict__ rp1,
    const int* __restrict__ col1, const short* __restrict__ X2,
    const int* __restrict__ rp2, const int* __restrict__ col2,
    short* __restrict__ out, int N) {
  int g = blockIdx.x * 16 + (int)threadIdx.x / 16;
  int c = (int)threadIdx.x % 16;
  if (g >= N) return;
  float tot[8] = {0.f, 0.f, 0.f, 0.f, 0.f, 0.f, 0.f, 0.f};
  {
    int s = rp1[g], e = rp1[g + 1];
    float a[8] = {0.f, 0.f, 0.f, 0.f, 0.f, 0.f, 0.f, 0.f};
    gacc(reinterpret_cast<const short8*>(X1), 16, c, col1, s, e, a);
    float inv = 1.0f / fmaxf((float)(e - s), 1.0f);
#pragma unroll
    for (int i = 0; i < 8; ++i) tot[i] += a[i] * inv;
  }
  {
    int s = rp2[g], e = rp2[g + 1];
    float a[8] = {0.f, 0.f, 0.f, 0.f, 0.f, 0.f, 0.f, 0.f};
    gacc(reinterpret_cast<const short8*>(X2), 16, c, col2, s, e, a);
    float inv = 1.0f / fmaxf((float)(e - s), 1.0f);
#pragma unroll
    for (int i = 0; i < 8; ++i) tot[i] += a[i] * inv;
  }
  short8 w;
#pragma unroll
  for (int i = 0; i < 8; ++i) w[i] = f2bf(tot[i]);
  reinterpret_cast<short8*>(out)[(size_t)g * 16 + c] = w;
}

// ------- MFMA GEMM v5 (unchanged): 8 waves, B-first, gll dbuf ----------------
template <int K, int DOUT, int NA, bool BF16OUT, bool BIAS, bool RELU,
          bool HASADD>
__global__ __launch_bounds__(512, 4) void mfma_gemm(
    const short* __restrict__ A0, const short* __restrict__ A1,
    const short* __restrict__ A2, const short* __restrict__ B0,
    const short* __restrict__ B1, const short* __restrict__ B2,
    const float* __restrict__ bias, const short* __restrict__ add0,
    float* __restrict__ Cf, short* __restrict__ Cb, int N) {
  constexpr int WC = (DOUT == 256) ? 8 : 4;
  constexpr int WR = 8 / WC;
  constexpr int TM = 4 / WR;
  constexpr int TN = DOUT / WC / 16;
  constexpr int CPK = K / 128;
  constexpr int NCHUNK = NA * CPK;
  constexpr int KCH = K / 32;

  __shared__ short As[2][64 * 128];

  const int tid = threadIdx.x;
  const int lane = tid & 63;
  const int w = tid >> 6;
  const int wc = w % WC;
  const int wr = w / WC;
  const int lr = lane & 15;
  const int ls = lane >> 4;
  const int n0 = blockIdx.x * 64;

  const short* Ap[3] = {A0, A1, A2};
  const short* Bp[3] = {B0, B1, B2};

  auto stage = [&](int buf, int a, int kc) {
#pragma unroll
    for (int it = 0; it < 2; ++it) {
      int u = it * 512 + w * 64 + lane;
      int row = u >> 4;
      int c8s = u & 15;
      int n = n0 + row;
      if (n >= N) n = N - 1;
      const short* g = Ap[a] + (size_t)n * K + kc + ((c8s ^ (row & 7)) << 3);
      short* l = &As[buf][(it * 512 + w * 64) * 8];
      __builtin_amdgcn_global_load_lds(
          (const __attribute__((address_space(1))) void*)g,
          (__attribute__((address_space(3))) void*)l, 16, 0, 0);
    }
  };

  f32x4 acc[TM][TN] = {};

  stage(0, 0, 0);
  __syncthreads();

#pragma unroll
  for (int c = 0; c < NCHUNK; ++c) {
    const int buf = c & 1;
    const int a = c / CPK;
    const int kc32 = (c % CPK) * 4;
    const short* Ba = Bp[a];

    short8 bfr[4][TN];
#pragma unroll
    for (int kk = 0; kk < 4; ++kk)
#pragma unroll
      for (int tn = 0; tn < TN; ++tn)
        bfr[kk][tn] = *reinterpret_cast<const short8*>(
            Ba + ((size_t)((wc * TN + tn) * KCH + kc32 + kk) * 64 + lane) * 8);
    __builtin_amdgcn_sched_barrier(0);
    if (c + 1 < NCHUNK)
      stage(buf ^ 1, (c + 1) / CPK, ((c + 1) % CPK) * 128);
    __builtin_amdgcn_sched_barrier(0);
#pragma unroll
    for (int kk = 0; kk < 4; ++kk) {
#pragma unroll
      for (int tm = 0; tm < TM; ++tm) {
        int row = wr * TM * 16 + tm * 16 + lr;
        short8 af = *reinterpret_cast<const short8*>(
            &As[buf][(row * 128 + (kk * 4 + ls) * 8) ^ ((row & 7) << 3)]);
#pragma unroll
        for (int tn = 0; tn < TN; ++tn)
          acc[tm][tn] = __builtin_amdgcn_mfma_f32_16x16x32_bf16(
              af, bfr[kk][tn], acc[tm][tn], 0, 0, 0);
      }
    }
    __syncthreads();
  }

#pragma unroll
  for (int tm = 0; tm < TM; ++tm) {
#pragma unroll
    for (int tn = 0; tn < TN; ++tn) {
      int colg = wc * TN * 16 + tn * 16 + lr;
      float bv = 0.f;
      if constexpr (BIAS) bv = bias[colg];
#pragma unroll
      for (int r = 0; r < 4; ++r) {
        int n = n0 + wr * TM * 16 + tm * 16 + ls * 4 + r;
        if (n < N) {
          float v = acc[tm][tn][r] + bv;
          if constexpr (HASADD) v += bf2f(add0[(size_t)n * DOUT + colg]);
          if constexpr (RELU) v = fmaxf(v, 0.f);
          if constexpr (BF16OUT)
            Cb[(size_t)n * DOUT + colg] = f2bf(v);
          else
            Cf[(size_t)n * DOUT + colg] = v;
        }
      }
    }
  }
}

}  // namespace

extern "C" void kernel_launch(void* const* d_in, const int* in_sizes, int n_in,
                              void* d_out, int out_size, void* d_ws,
                              size_t ws_size, hipStream_t stream) {
  const float* x_p   = (const float*)d_in[0];
  const float* x_t   = (const float*)d_in[1];
  const float* x_a   = (const float*)d_in[2];
  const float* emb_p = (const float*)d_in[3];
  const float* emb_a = (const float*)d_in[4];
  const float* W1l   = (const float*)d_in[5];
  const float* b1    = (const float*)d_in[6];
  const float* W1r   = (const float*)d_in[7];
  const float* W2l   = (const float*)d_in[8];
  const float* b2    = (const float*)d_in[9];
  const float* W2r   = (const float*)d_in[10];
  const float* Wres  = (const float*)d_in[11];
  const float* bres  = (const float*)d_in[12];
  const int* e_pt = (const int*)d_in[13];
  const int* e_tp = (const int*)d_in[14];
  const int* e_at = (const int*)d_in[15];
  const int* e_ta = (const int*)d_in[16];
  (void)in_sizes; (void)n_in; (void)out_size; (void)ws_size;

  float* out = (float*)d_out;
  float* p_out = out;
  float* t_out = out + (size_t)kNP * DO;
  float* a_out = out + (size_t)(kNP + kNT) * DO;

  char* base = (char*)d_ws;
  size_t off = 0;
  auto alloc = [&](size_t bytes) {
    off = (off + 255) & ~size_t(255);
    void* p = base + off;
    off += bytes;
    return p;
  };

  short* t1b   = (short*)alloc((size_t)kNT * DH * 2);
  short* p1b   = (short*)alloc((size_t)kNP * DH * 2);
  short* a1b   = (short*)alloc((size_t)kNA * DH * 2);
  short* aggpt = (short*)alloc((size_t)kNT * DIN * 2);  // later: gt, then ypab
  short* aggat = (short*)alloc((size_t)kNT * DIN * 2);  // (ypab spans these)
  short* aggtp = (short*)alloc((size_t)kNP * DIN * 2);
  short* aggta = (short*)alloc((size_t)kNA * DIN * 2);
  short* xpeb  = (short*)alloc((size_t)kNP * DIN * 2);
  short* xaeb  = (short*)alloc((size_t)kNA * DIN * 2);
  short* xtb   = (short*)alloc((size_t)kNT * DIN * 2);
  short* ypb   = (short*)alloc((size_t)kNP * DO * 2);
  short* yab   = (short*)alloc((size_t)kNA * DO * 2);
  short* g_tp  = (short*)alloc((size_t)kNP * DO * 2);
  short* g_ta  = (short*)alloc((size_t)kNA * DO * 2);
  short* w1l_rm  = (short*)alloc(4 * per1 * 2);
  short* w1r_rm  = (short*)alloc(4 * per1 * 2);
  short* w1rc_rm = (short*)alloc(per1 * 2);
  short* w2l_rm  = (short*)alloc(4 * per2 * 2);
  short* wc_rm   = (short*)alloc(3 * per2 * 2);
  short* w1lb   = (short*)alloc(4 * per1 * 2);
  short* w1rb   = (short*)alloc(4 * per1 * 2);
  short* w1rcb  = (short*)alloc(per1 * 2);
  short* w2lb   = (short*)alloc(4 * per2 * 2);
  short* wcb    = (short*)alloc(3 * per2 * 2);
  short* w2lpab = (short*)alloc(2 * per2 * 2);
  float* bc     = (float*)alloc(3 * DO * 4);
  float* b1ct   = (float*)alloc(DH * 4);

  int* rp_pt  = (int*)alloc((kNT + 1) * 4);
  int* rp_tp  = (int*)alloc((kNP + 1) * 4);
  int* rp_at  = (int*)alloc((kNT + 1) * 4);
  int* rp_ta  = (int*)alloc((kNA + 1) * 4);
  int* col_pt = (int*)alloc(kEPT * 4);
  int* col_tp = (int*)alloc(kETP * 4);
  int* col_at = (int*)alloc(kEAT * 4);
  int* col_ta = (int*)alloc(kETA * 4);
  int* bh     = (int*)alloc(NBTOT * 4);
  int* bb     = (int*)alloc(BBTOT * 4);
  int* gcur   = (int*)alloc(NBTOT * 4);
  int* bin    = (int*)alloc((size_t)(kEPT + kETP + kEAT + kETA) * 4);

  // ---- 0. fused converts ----
  {
    int tot = kNP * DIN / 8 + kNA * DIN / 8 + kNT * DIN / 8;
    cvt_all<<<cdiv(tot, 256), 256, 0, stream>>>(x_p, emb_p, xpeb, x_a, emb_a,
                                                xaeb, x_t, xtb);
  }

  // ---- 1. fused weight prep + fragment swizzle ----
  {
    int tot = 4 * per1 + 4 * per1 + per1 + 4 * per2 + 3 * per2 + DH;
    prep_all<<<cdiv(tot, 256), 256, 0, stream>>>(
        W1l, W1r, W2l, Wres, W2r, bres, b2, b1, w1l_rm, w1r_rm, w1rc_rm,
        w2l_rm, wc_rm, bc, b1ct);
    swizzle_all<<<cdiv(73728, 256), 256, 0, stream>>>(
        w1l_rm, w1lb, w1r_rm, w1rb, w1rc_rm, w1rcb, w2l_rm, w2lb, wc_rm, wcb,
        w2lpab);
  }

  // ---- 2. CSR build v2 (bucketed counting sort) ----
  hipMemsetAsync(bh, 0, NBTOT * 4, stream);
  bucket_hist<<<CBTOT, 256, 0, stream>>>(e_pt, e_tp, e_at, e_ta, bh);
  bucket_scan<<<4, 1024, 0, stream>>>(bh, bb, gcur);
  bin_edges<<<CBTOT, 256, 0, stream>>>(e_pt, e_tp, e_at, e_ta, gcur, bin);
  fine_fill<<<NBTOT, 256, 0, stream>>>(bin, bb, rp_pt, rp_tp, rp_at, rp_ta,
                                       col_pt, col_tp, col_at, col_ta);

  // ---- 3. conv1 gathers (one launch) ----
  gather4<<<cdiv(2 * kNT + kNP + kNA, 16), 256, 0, stream>>>(
      xpeb, xaeb, xtb, rp_pt, col_pt, aggpt, rp_at, col_at, aggat, rp_tp,
      col_tp, aggtp, rp_ta, col_ta, aggta);

  // ---- 4. conv1 GEMMs ----
  mfma_gemm<DIN, DH, 3, true, true, true, false>
      <<<cdiv(kNT, 64), 512, 0, stream>>>(aggpt, aggat, xtb, w1lb,
                                          w1lb + 2 * per1, w1rcb, b1ct, nullptr,
                                          nullptr, t1b, kNT);
  mfma_gemm<DIN, DH, 2, true, true, true, false>
      <<<cdiv(kNP, 64), 512, 0, stream>>>(aggtp, xpeb, nullptr, w1lb + 1 * per1,
                                          w1rb + 1 * per1, nullptr, b1 + 1 * DH,
                                          nullptr, nullptr, p1b, kNP);
  mfma_gemm<DIN, DH, 2, true, true, true, false>
      <<<cdiv(kNA, 64), 512, 0, stream>>>(aggta, xaeb, nullptr, w1lb + 3 * per1,
                                          w1rb + 3 * per1, nullptr, b1 + 3 * DH,
                                          nullptr, nullptr, a1b, kNA);

  // ---- 5. conv2 down-projections for the track terms ----
  mfma_gemm<DH, DO, 1, true, false, false, false>
      <<<cdiv(kNP, 64), 512, 0, stream>>>(p1b, nullptr, nullptr, w2lb, nullptr,
                                          nullptr, nullptr, nullptr, nullptr,
                                          ypb, kNP);
  mfma_gemm<DH, DO, 1, true, false, false, false>
      <<<cdiv(kNA, 64), 512, 0, stream>>>(a1b, nullptr, nullptr,
                                          w2lb + 2 * per2, nullptr, nullptr,
                                          nullptr, nullptr, nullptr, yab, kNA);

  // ---- 6. gt = mean_pt(y_p) + mean_at(y_a), fused t_out GEMM ----
  short* gt = aggpt;  // free after conv1-t GEMM
  gather2_b<<<cdiv(kNT, 16), 256, 0, stream>>>(ypb, rp_pt, col_pt, yab, rp_at,
                                               col_at, gt, kNT);
  mfma_gemm<DH, DO, 1, false, true, false, true>
      <<<cdiv(kNT, 64), 512, 0, stream>>>(t1b, nullptr, nullptr, wcb, nullptr,
                                          nullptr, bc, gt, t_out, nullptr,
                                          kNT);

  // ---- 7. y_pa = t1 @ [W2l1;W2l3]^T ----
  short* ypab = aggpt;  // spans aggpt..aggat region
  mfma_gemm<DH, 256, 1, true, false, false, false>
      <<<cdiv(kNT, 64), 512, 0, stream>>>(t1b, nullptr, nullptr, w2lpab,
                                          nullptr, nullptr, nullptr, nullptr,
                                          nullptr, ypab, kNT);

  // ---- 8. conv2 tp/ta gathers (one launch) ----
  gather_tpta<<<cdiv(kNP + kNA, 16), 256, 0, stream>>>(
      ypab, rp_tp, col_tp, g_tp, rp_ta, col_ta, g_ta);

  // ---- 9. p_out / a_out ----
  mfma_gemm<DH, DO, 1, false, true, false, true>
      <<<cdiv(kNP, 64), 512, 0, stream>>>(p1b, nullptr, nullptr, wcb + per2,
                                          nullptr, nullptr, bc + DO, g_tp,
                                          p_out, nullptr, kNP);
  mfma_gemm<DH, DO, 1, false, true, false, true>
      <<<cdiv(kNA, 64), 512, 0, stream>>>(a1b, nullptr, nullptr,
                                          wcb + 2 * per2, nullptr, nullptr,
                                          bc + 2 * DO, g_ta, a_out, nullptr,
                                          kNA);
}